// Round 1
// baseline (248.726 us; speedup 1.0000x reference)
//
#include <hip/hip_runtime.h>
#include <hip/hip_bf16.h>

// B=8, T=4096, C=1024, HS=64. Single attention head, causal, scale = C^-0.5.
// Pipeline: wprep (W -> Wt bf16 [192][1024]) ; proj (q,k bf16 [b][t][64], vT bf16 [b][64][t]) ;
//           flash (causal online-softmax attention, bf16 MFMA, fp32 out).

typedef __attribute__((ext_vector_type(8))) short short8;
typedef __attribute__((ext_vector_type(4))) float f32x4;

#define NB 8
#define NT 4096
#define NC 1024
#define NH 64

__device__ __forceinline__ unsigned short f2bf(float f) {
    unsigned int u = __builtin_bit_cast(unsigned int, f);
    u += 0x7fffu + ((u >> 16) & 1u);   // RNE
    return (unsigned short)(u >> 16);
}

// ---------------- W prep: Wt[n][c] = W_{n/64}[c][n%64] as bf16 -----------------
__global__ __launch_bounds__(256) void wprep_kernel(
    const float* __restrict__ Wk, const float* __restrict__ Wq,
    const float* __restrict__ Wv, unsigned short* __restrict__ Wt)
{
    int n = blockIdx.x;            // 0..191
    int which = n >> 6, h = n & 63;
    const float* W = (which == 0) ? Wk : (which == 1) ? Wq : Wv;
    for (int c = threadIdx.x; c < NC; c += 256)
        Wt[(size_t)n * NC + c] = f2bf(W[(size_t)c * NH + h]);
}

// ---------------- Projection GEMM: [32768 x 1024] @ [1024 x 192] ---------------
// 512 blocks x 256 thr (4 waves). Wave computes 16 rows x 192 cols.
// A-frags loaded directly from global fp32 x (one 128B line per row per k-step).
// B-frags loaded directly from global Wt (tiny, L2-resident).
__global__ __launch_bounds__(256) void proj_kernel(
    const float* __restrict__ x, const unsigned short* __restrict__ Wt,
    unsigned short* __restrict__ qws, unsigned short* __restrict__ kws,
    unsigned short* __restrict__ vtws)
{
    const int lane = threadIdx.x & 63;
    const int wave = threadIdx.x >> 6;
    const int l15 = lane & 15;
    const int kg = lane >> 4;                  // 0..3
    const int m0 = blockIdx.x * 64;
    const int arow = m0 + wave * 16 + l15;     // A-operand row

    f32x4 acc[12];
#pragma unroll
    for (int i = 0; i < 12; ++i) acc[i] = f32x4{0.f, 0.f, 0.f, 0.f};

    const float* xp = x + (size_t)arow * NC + kg * 8;
    const unsigned short* wp = Wt + (size_t)l15 * NC + kg * 8;

    for (int kc = 0; kc < 32; ++kc) {          // K chunks of 32
        float4 f0 = *(const float4*)(xp + kc * 32);
        float4 f1 = *(const float4*)(xp + kc * 32 + 4);
        short8 a;
        a[0] = (short)f2bf(f0.x); a[1] = (short)f2bf(f0.y);
        a[2] = (short)f2bf(f0.z); a[3] = (short)f2bf(f0.w);
        a[4] = (short)f2bf(f1.x); a[5] = (short)f2bf(f1.y);
        a[6] = (short)f2bf(f1.z); a[7] = (short)f2bf(f1.w);
#pragma unroll
        for (int nt = 0; nt < 12; ++nt) {
            short8 b = *(const short8*)(wp + (size_t)nt * 16 * NC + kc * 32);
            acc[nt] = __builtin_amdgcn_mfma_f32_16x16x32_bf16(a, b, acc[nt], 0, 0, 0);
        }
    }

    // C/D layout: col = lane&15, row = (lane>>4)*4 + reg  [HW-verified]
    const int crow0 = m0 + wave * 16 + (kg << 2);
#pragma unroll
    for (int nt = 0; nt < 12; ++nt) {
        int n = nt * 16 + l15;
        int which = n >> 6;
        int h = n & 63;
#pragma unroll
        for (int r = 0; r < 4; ++r) {
            int gm = crow0 + r;
            unsigned short v = f2bf(acc[nt][r]);
            if (which == 0) {
                kws[(size_t)gm * NH + h] = v;
            } else if (which == 1) {
                qws[(size_t)gm * NH + h] = v;
            } else {
                int bb = gm >> 12, tt = gm & 4095;
                vtws[((size_t)(bb * NH + h)) * NT + tt] = v;
            }
        }
    }
}

// ---------------- Flash attention (causal) -------------------------------------
// 512 blocks (8 batches x 64 q-tiles of 64 rows), 4 waves x 16 q-rows each.
// KV tiles of 64 keys. K tile [64 keys][64 d], V tile stored transposed [64 d][64 keys].
// All LDS tiles XOR-swizzled: byte ^= (row&7)<<4 (rows are 128B).
__global__ __launch_bounds__(256) void flash_kernel(
    const unsigned short* __restrict__ qws, const unsigned short* __restrict__ kws,
    const unsigned short* __restrict__ vtws, float* __restrict__ out)
{
    __shared__ unsigned short Klds[64 * 64];
    __shared__ unsigned short Vlds[64 * 64];
    __shared__ unsigned short Plds[4 * 16 * 64];   // per-wave 16x64 P strips

    const int id = blockIdx.x;
    const int b = id & 7;
    const int qt = 63 - (id >> 3);   // heavy tiles first for load balance
    const int lane = threadIdx.x & 63;
    const int wave = threadIdx.x >> 6;
    const int l15 = lane & 15;
    const int kg = lane >> 4;

    // Q fragments, kept in registers for the whole block
    short8 qf[2];
    {
        const unsigned short* qp =
            qws + ((size_t)(b * NT + qt * 64 + wave * 16 + l15)) * NH + kg * 8;
        qf[0] = *(const short8*)(qp);
        qf[1] = *(const short8*)(qp + 32);
    }

    f32x4 o[4];
#pragma unroll
    for (int dt = 0; dt < 4; ++dt) o[dt] = f32x4{0.f, 0.f, 0.f, 0.f};
    float m_r[4], l_r[4];
#pragma unroll
    for (int r = 0; r < 4; ++r) { m_r[r] = -INFINITY; l_r[r] = 0.f; }

    // staging assignment: thread -> (row 0..63, seg 0..3 of 32B)
    const int stg_row = threadIdx.x >> 2;
    const int stg_seg = threadIdx.x & 3;
    const unsigned short* kbase =
        kws + ((size_t)(b * NT) + stg_row) * NH + stg_seg * 16;
    const unsigned short* vbase =
        vtws + ((size_t)(b * NH + stg_row)) * NT + stg_seg * 16;
    const int sc0 = (stg_seg * 32) ^ ((stg_row & 7) << 4);
    const int sc1 = (stg_seg * 32 + 16) ^ ((stg_row & 7) << 4);
    char* kdst = (char*)Klds + stg_row * 128;
    char* vdst = (char*)Vlds + stg_row * 128;
    char* pw = (char*)Plds + wave * 2048;

    const float cs = 0.04508422f;   // log2(e) / 32

    for (int kv = 0; kv <= qt; ++kv) {
        __syncthreads();            // previous iter's LDS reads done
        {
            const uint4* kg4 = (const uint4*)(kbase + (size_t)kv * 64 * NH);
            uint4 k0 = kg4[0], k1 = kg4[1];
            const uint4* vg4 = (const uint4*)(vbase + kv * 64);
            uint4 v0 = vg4[0], v1 = vg4[1];
            *(uint4*)(kdst + sc0) = k0;
            *(uint4*)(kdst + sc1) = k1;
            *(uint4*)(vdst + sc0) = v0;
            *(uint4*)(vdst + sc1) = v1;
        }
        __syncthreads();

        // S = Q K^T  (wave strip: 16 q-rows x 64 keys)
        f32x4 s[4];
#pragma unroll
        for (int jt = 0; jt < 4; ++jt) s[jt] = f32x4{0.f, 0.f, 0.f, 0.f};
#pragma unroll
        for (int ks = 0; ks < 2; ++ks) {
            const int cbb = ks * 64 + kg * 16;
#pragma unroll
            for (int jt = 0; jt < 4; ++jt) {
                int krow = jt * 16 + l15;
                short8 kf = *(const short8*)((char*)Klds + krow * 128 +
                                             (cbb ^ ((krow & 7) << 4)));
                s[jt] = __builtin_amdgcn_mfma_f32_16x16x32_bf16(qf[ks], kf, s[jt], 0, 0, 0);
            }
        }

        // scale to log2 domain + causal mask (only diagonal tile needs masking)
        const bool diag = (kv == qt);
        const int irow0 = wave * 16 + (kg << 2);
        (void)irow0;
#pragma unroll
        for (int jt = 0; jt < 4; ++jt) {
            int jl = jt * 16 + l15;
#pragma unroll
            for (int r = 0; r < 4; ++r) {
                float v = s[jt][r] * cs;
                int il = (kg << 2) + r;  // local row within 64-row q-tile offset by wave*16
                if (diag && (jl > wave * 16 + il)) v = -1e30f;
                s[jt][r] = v;
            }
        }

        // row max over 64 keys: 4 jt-tiles then 16-lane butterfly
        float pmax[4];
#pragma unroll
        for (int r = 0; r < 4; ++r)
            pmax[r] = fmaxf(fmaxf(s[0][r], s[1][r]), fmaxf(s[2][r], s[3][r]));
#pragma unroll
        for (int off = 1; off < 16; off <<= 1)
#pragma unroll
            for (int r = 0; r < 4; ++r)
                pmax[r] = fmaxf(pmax[r], __shfl_xor(pmax[r], off));

        float alpha[4];
#pragma unroll
        for (int r = 0; r < 4; ++r) {
            float mn = fmaxf(m_r[r], pmax[r]);
            alpha[r] = exp2f(m_r[r] - mn);
            m_r[r] = mn;
        }

        // P = exp2(S - m), row sums
        float psum[4];
#pragma unroll
        for (int jt = 0; jt < 4; ++jt)
#pragma unroll
            for (int r = 0; r < 4; ++r)
                s[jt][r] = exp2f(s[jt][r] - m_r[r]);
#pragma unroll
        for (int r = 0; r < 4; ++r)
            psum[r] = (s[0][r] + s[1][r]) + (s[2][r] + s[3][r]);
#pragma unroll
        for (int off = 1; off < 16; off <<= 1)
#pragma unroll
            for (int r = 0; r < 4; ++r)
                psum[r] += __shfl_xor(psum[r], off);
#pragma unroll
        for (int r = 0; r < 4; ++r)
            l_r[r] = l_r[r] * alpha[r] + psum[r];
#pragma unroll
        for (int dt = 0; dt < 4; ++dt)
#pragma unroll
            for (int r = 0; r < 4; ++r)
                o[dt][r] *= alpha[r];

        // P (C-layout) -> LDS bf16, swizzled to match A-frag reads
#pragma unroll
        for (int jt = 0; jt < 4; ++jt) {
            int jl = jt * 16 + l15;
#pragma unroll
            for (int r = 0; r < 4; ++r) {
                int ir = (kg << 2) + r;
                *(unsigned short*)(pw + ir * 128 + ((jl * 2) ^ ((ir & 7) << 4))) =
                    f2bf(s[jt][r]);
            }
        }
        __syncthreads();   // intra-wave LDS write->read ordering (uniform barrier)

        // O += P @ V   (A = P strip, B = V^T rows)
#pragma unroll
        for (int ks = 0; ks < 2; ++ks) {
            const int cbb = ks * 64 + kg * 16;
            short8 pf = *(const short8*)(pw + l15 * 128 + (cbb ^ ((l15 & 7) << 4)));
#pragma unroll
            for (int dt = 0; dt < 4; ++dt) {
                int vrow = dt * 16 + l15;
                short8 vf = *(const short8*)((char*)Vlds + vrow * 128 +
                                             (cbb ^ ((vrow & 7) << 4)));
                o[dt] = __builtin_amdgcn_mfma_f32_16x16x32_bf16(pf, vf, o[dt], 0, 0, 0);
            }
        }
    }

    // epilogue: normalize and store fp32
    float linv[4];
#pragma unroll
    for (int r = 0; r < 4; ++r) linv[r] = 1.0f / l_r[r];
    size_t obase = ((size_t)b * NT + (size_t)qt * 64 + wave * 16 + (kg << 2)) * NH;
#pragma unroll
    for (int dt = 0; dt < 4; ++dt)
#pragma unroll
        for (int r = 0; r < 4; ++r)
            out[obase + (size_t)r * NH + dt * 16 + l15] = o[dt][r] * linv[r];
}

extern "C" void kernel_launch(void* const* d_in, const int* in_sizes, int n_in,
                              void* d_out, int out_size, void* d_ws, size_t ws_size,
                              hipStream_t stream) {
    const float* x  = (const float*)d_in[0];
    const float* Wk = (const float*)d_in[1];
    const float* Wq = (const float*)d_in[2];
    const float* Wv = (const float*)d_in[3];
    float* out = (float*)d_out;

    unsigned short* ws   = (unsigned short*)d_ws;
    const size_t qkv_elems = (size_t)NB * NT * NH;   // 2M elements each
    unsigned short* qws  = ws;
    unsigned short* kws  = qws + qkv_elems;
    unsigned short* vtws = kws + qkv_elems;
    unsigned short* Wt   = vtws + qkv_elems;          // 192*1024 bf16

    wprep_kernel<<<dim3(192), dim3(256), 0, stream>>>(Wk, Wq, Wv, Wt);
    proj_kernel<<<dim3(512), dim3(256), 0, stream>>>(x, Wt, qws, kws, vtws);
    flash_kernel<<<dim3(512), dim3(256), 0, stream>>>(qws, kws, vtws, out);
}

// Round 2
// 225.655 us; speedup vs baseline: 1.1022x; 1.1022x over previous
//
#include <hip/hip_runtime.h>
#include <hip/hip_bf16.h>

// B=8, T=4096, C=1024, HS=64. Single attention head, causal, scale = C^-0.5.
// Pipeline: wprep (W -> Wt bf16 [192][1024]) ; proj (q,k bf16 [b][t][64], vT bf16 [b][64][t]) ;
//           flash (causal online-softmax attention, bf16 MFMA, fp32 out).

typedef __attribute__((ext_vector_type(8))) short short8;
typedef __attribute__((ext_vector_type(4))) float f32x4;

#define NB 8
#define NT 4096
#define NC 1024
#define NH 64

__device__ __forceinline__ unsigned short f2bf(float f) {
    unsigned int u = __builtin_bit_cast(unsigned int, f);
    u += 0x7fffu + ((u >> 16) & 1u);   // RNE
    return (unsigned short)(u >> 16);
}

// ---------------- W prep: Wt[n][c] = W_{n/64}[c][n%64] as bf16 -----------------
__global__ __launch_bounds__(256) void wprep_kernel(
    const float* __restrict__ Wk, const float* __restrict__ Wq,
    const float* __restrict__ Wv, unsigned short* __restrict__ Wt)
{
    int n = blockIdx.x;            // 0..191
    int which = n >> 6, h = n & 63;
    const float* W = (which == 0) ? Wk : (which == 1) ? Wq : Wv;
    for (int c = threadIdx.x; c < NC; c += 256)
        Wt[(size_t)n * NC + c] = f2bf(W[(size_t)c * NH + h]);
}

// ---------------- Projection GEMM: [32768 x 1024] @ [1024 x 192] ---------------
// 512 blocks x 256 thr (4 waves). Wave computes 16 rows x 192 cols.
// Register-pipelined: depth-1 prefetch of A (x, fp32) and all 12 B-frags (Wt).
// __launch_bounds__(256,2): grid caps us at 2 waves/SIMD anyway -> let the
// backend use up to ~256 VGPRs and schedule for ILP instead of occupancy.
__global__ __launch_bounds__(256, 2) void proj_kernel(
    const float* __restrict__ x, const unsigned short* __restrict__ Wt,
    unsigned short* __restrict__ qws, unsigned short* __restrict__ kws,
    unsigned short* __restrict__ vtws)
{
    const int lane = threadIdx.x & 63;
    const int wave = threadIdx.x >> 6;
    const int l15 = lane & 15;
    const int kg = lane >> 4;                  // 0..3
    const int m0 = blockIdx.x * 64;
    const int arow = m0 + wave * 16 + l15;     // A-operand row

    f32x4 acc[12];
#pragma unroll
    for (int i = 0; i < 12; ++i) acc[i] = f32x4{0.f, 0.f, 0.f, 0.f};

    const float* xp = x + (size_t)arow * NC + kg * 8;
    const unsigned short* wp = Wt + (size_t)l15 * NC + kg * 8;

    // prefetch chunk 0
    short8 b[12];
#pragma unroll
    for (int nt = 0; nt < 12; ++nt)
        b[nt] = *(const short8*)(wp + (size_t)nt * 16 * NC);
    float4 f0 = *(const float4*)(xp);
    float4 f1 = *(const float4*)(xp + 4);

    for (int kc = 0; kc < 32; ++kc) {          // K chunks of 32
        // issue prefetch for chunk kc+1 (independent of this chunk's MFMAs)
        short8 bn[12];
        float4 g0, g1;
        if (kc < 31) {
#pragma unroll
            for (int nt = 0; nt < 12; ++nt)
                bn[nt] = *(const short8*)(wp + (size_t)nt * 16 * NC + (kc + 1) * 32);
            g0 = *(const float4*)(xp + (kc + 1) * 32);
            g1 = *(const float4*)(xp + (kc + 1) * 32 + 4);
        }

        short8 a;
        a[0] = (short)f2bf(f0.x); a[1] = (short)f2bf(f0.y);
        a[2] = (short)f2bf(f0.z); a[3] = (short)f2bf(f0.w);
        a[4] = (short)f2bf(f1.x); a[5] = (short)f2bf(f1.y);
        a[6] = (short)f2bf(f1.z); a[7] = (short)f2bf(f1.w);
#pragma unroll
        for (int nt = 0; nt < 12; ++nt)
            acc[nt] = __builtin_amdgcn_mfma_f32_16x16x32_bf16(a, b[nt], acc[nt], 0, 0, 0);

#pragma unroll
        for (int nt = 0; nt < 12; ++nt) b[nt] = bn[nt];
        f0 = g0; f1 = g1;
    }

    // C/D layout: col = lane&15, row = (lane>>4)*4 + reg  [HW-verified]
    const int crow0 = m0 + wave * 16 + (kg << 2);
#pragma unroll
    for (int nt = 0; nt < 12; ++nt) {
        int n = nt * 16 + l15;
        int which = n >> 6;
        int h = n & 63;
#pragma unroll
        for (int r = 0; r < 4; ++r) {
            int gm = crow0 + r;
            unsigned short v = f2bf(acc[nt][r]);
            if (which == 0) {
                kws[(size_t)gm * NH + h] = v;
            } else if (which == 1) {
                qws[(size_t)gm * NH + h] = v;
            } else {
                int bb = gm >> 12, tt = gm & 4095;
                vtws[((size_t)(bb * NH + h)) * NT + tt] = v;
            }
        }
    }
}

// ---------------- Flash attention (causal) -------------------------------------
// 512 blocks (8 batches x 64 q-tiles of 64 rows), 4 waves x 16 q-rows each.
// KV tiles of 64 keys. K tile [64 keys][64 d], V tile stored transposed [64 d][64 keys].
// All LDS tiles XOR-swizzled: byte ^= (row&7)<<4 (rows are 128B).
__global__ __launch_bounds__(256) void flash_kernel(
    const unsigned short* __restrict__ qws, const unsigned short* __restrict__ kws,
    const unsigned short* __restrict__ vtws, float* __restrict__ out)
{
    __shared__ unsigned short Klds[64 * 64];
    __shared__ unsigned short Vlds[64 * 64];
    __shared__ unsigned short Plds[4 * 16 * 64];   // per-wave 16x64 P strips

    const int id = blockIdx.x;
    const int b = id & 7;
    const int qt = 63 - (id >> 3);   // heavy tiles first for load balance
    const int lane = threadIdx.x & 63;
    const int wave = threadIdx.x >> 6;
    const int l15 = lane & 15;
    const int kg = lane >> 4;

    // Q fragments, kept in registers for the whole block
    short8 qf[2];
    {
        const unsigned short* qp =
            qws + ((size_t)(b * NT + qt * 64 + wave * 16 + l15)) * NH + kg * 8;
        qf[0] = *(const short8*)(qp);
        qf[1] = *(const short8*)(qp + 32);
    }

    f32x4 o[4];
#pragma unroll
    for (int dt = 0; dt < 4; ++dt) o[dt] = f32x4{0.f, 0.f, 0.f, 0.f};
    float m_r[4], l_r[4];
#pragma unroll
    for (int r = 0; r < 4; ++r) { m_r[r] = -INFINITY; l_r[r] = 0.f; }

    // staging assignment: thread -> (row 0..63, seg 0..3 of 32B)
    const int stg_row = threadIdx.x >> 2;
    const int stg_seg = threadIdx.x & 3;
    const unsigned short* kbase =
        kws + ((size_t)(b * NT) + stg_row) * NH + stg_seg * 16;
    const unsigned short* vbase =
        vtws + ((size_t)(b * NH + stg_row)) * NT + stg_seg * 16;
    const int sc0 = (stg_seg * 32) ^ ((stg_row & 7) << 4);
    const int sc1 = (stg_seg * 32 + 16) ^ ((stg_row & 7) << 4);
    char* kdst = (char*)Klds + stg_row * 128;
    char* vdst = (char*)Vlds + stg_row * 128;
    char* pw = (char*)Plds + wave * 2048;

    const float cs = 0.04508422f;   // log2(e) / 32

    for (int kv = 0; kv <= qt; ++kv) {
        __syncthreads();            // previous iter's LDS reads done
        {
            const uint4* kg4 = (const uint4*)(kbase + (size_t)kv * 64 * NH);
            uint4 k0 = kg4[0], k1 = kg4[1];
            const uint4* vg4 = (const uint4*)(vbase + kv * 64);
            uint4 v0 = vg4[0], v1 = vg4[1];
            *(uint4*)(kdst + sc0) = k0;
            *(uint4*)(kdst + sc1) = k1;
            *(uint4*)(vdst + sc0) = v0;
            *(uint4*)(vdst + sc1) = v1;
        }
        __syncthreads();

        // S = Q K^T  (wave strip: 16 q-rows x 64 keys)
        f32x4 s[4];
#pragma unroll
        for (int jt = 0; jt < 4; ++jt) s[jt] = f32x4{0.f, 0.f, 0.f, 0.f};
#pragma unroll
        for (int ks = 0; ks < 2; ++ks) {
            const int cbb = ks * 64 + kg * 16;
#pragma unroll
            for (int jt = 0; jt < 4; ++jt) {
                int krow = jt * 16 + l15;
                short8 kf = *(const short8*)((char*)Klds + krow * 128 +
                                             (cbb ^ ((krow & 7) << 4)));
                s[jt] = __builtin_amdgcn_mfma_f32_16x16x32_bf16(qf[ks], kf, s[jt], 0, 0, 0);
            }
        }

        // scale to log2 domain + causal mask (only diagonal tile needs masking)
        const bool diag = (kv == qt);
#pragma unroll
        for (int jt = 0; jt < 4; ++jt) {
            int jl = jt * 16 + l15;
#pragma unroll
            for (int r = 0; r < 4; ++r) {
                float v = s[jt][r] * cs;
                int il = (kg << 2) + r;
                if (diag && (jl > wave * 16 + il)) v = -1e30f;
                s[jt][r] = v;
            }
        }

        // row max over 64 keys: 4 jt-tiles then 16-lane butterfly
        float pmax[4];
#pragma unroll
        for (int r = 0; r < 4; ++r)
            pmax[r] = fmaxf(fmaxf(s[0][r], s[1][r]), fmaxf(s[2][r], s[3][r]));
#pragma unroll
        for (int off = 1; off < 16; off <<= 1)
#pragma unroll
            for (int r = 0; r < 4; ++r)
                pmax[r] = fmaxf(pmax[r], __shfl_xor(pmax[r], off));

        float alpha[4];
#pragma unroll
        for (int r = 0; r < 4; ++r) {
            float mn = fmaxf(m_r[r], pmax[r]);
            alpha[r] = exp2f(m_r[r] - mn);
            m_r[r] = mn;
        }

        // P = exp2(S - m), row sums
        float psum[4];
#pragma unroll
        for (int jt = 0; jt < 4; ++jt)
#pragma unroll
            for (int r = 0; r < 4; ++r)
                s[jt][r] = exp2f(s[jt][r] - m_r[r]);
#pragma unroll
        for (int r = 0; r < 4; ++r)
            psum[r] = (s[0][r] + s[1][r]) + (s[2][r] + s[3][r]);
#pragma unroll
        for (int off = 1; off < 16; off <<= 1)
#pragma unroll
            for (int r = 0; r < 4; ++r)
                psum[r] += __shfl_xor(psum[r], off);
#pragma unroll
        for (int r = 0; r < 4; ++r)
            l_r[r] = l_r[r] * alpha[r] + psum[r];
#pragma unroll
        for (int dt = 0; dt < 4; ++dt)
#pragma unroll
            for (int r = 0; r < 4; ++r)
                o[dt][r] *= alpha[r];

        // P (C-layout) -> LDS bf16, swizzled to match A-frag reads
#pragma unroll
        for (int jt = 0; jt < 4; ++jt) {
            int jl = jt * 16 + l15;
#pragma unroll
            for (int r = 0; r < 4; ++r) {
                int ir = (kg << 2) + r;
                *(unsigned short*)(pw + ir * 128 + ((jl * 2) ^ ((ir & 7) << 4))) =
                    f2bf(s[jt][r]);
            }
        }
        __syncthreads();   // intra-wave LDS write->read ordering (uniform barrier)

        // O += P @ V   (A = P strip, B = V^T rows)
#pragma unroll
        for (int ks = 0; ks < 2; ++ks) {
            const int cbb = ks * 64 + kg * 16;
            short8 pf = *(const short8*)(pw + l15 * 128 + (cbb ^ ((l15 & 7) << 4)));
#pragma unroll
            for (int dt = 0; dt < 4; ++dt) {
                int vrow = dt * 16 + l15;
                short8 vf = *(const short8*)((char*)Vlds + vrow * 128 +
                                             (cbb ^ ((vrow & 7) << 4)));
                o[dt] = __builtin_amdgcn_mfma_f32_16x16x32_bf16(pf, vf, o[dt], 0, 0, 0);
            }
        }
    }

    // epilogue: normalize and store fp32
    float linv[4];
#pragma unroll
    for (int r = 0; r < 4; ++r) linv[r] = 1.0f / l_r[r];
    size_t obase = ((size_t)b * NT + (size_t)qt * 64 + wave * 16 + (kg << 2)) * NH;
#pragma unroll
    for (int dt = 0; dt < 4; ++dt)
#pragma unroll
        for (int r = 0; r < 4; ++r)
            out[obase + (size_t)r * NH + dt * 16 + l15] = o[dt][r] * linv[r];
}

extern "C" void kernel_launch(void* const* d_in, const int* in_sizes, int n_in,
                              void* d_out, int out_size, void* d_ws, size_t ws_size,
                              hipStream_t stream) {
    const float* x  = (const float*)d_in[0];
    const float* Wk = (const float*)d_in[1];
    const float* Wq = (const float*)d_in[2];
    const float* Wv = (const float*)d_in[3];
    float* out = (float*)d_out;

    unsigned short* ws   = (unsigned short*)d_ws;
    const size_t qkv_elems = (size_t)NB * NT * NH;   // 2M elements each
    unsigned short* qws  = ws;
    unsigned short* kws  = qws + qkv_elems;
    unsigned short* vtws = kws + qkv_elems;
    unsigned short* Wt   = vtws + qkv_elems;          // 192*1024 bf16

    wprep_kernel<<<dim3(192), dim3(256), 0, stream>>>(Wk, Wq, Wv, Wt);
    proj_kernel<<<dim3(512), dim3(256), 0, stream>>>(x, Wt, qws, kws, vtws);
    flash_kernel<<<dim3(512), dim3(256), 0, stream>>>(qws, kws, vtws, out);
}

// Round 3
// 161.156 us; speedup vs baseline: 1.5434x; 1.4002x over previous
//
#include <hip/hip_runtime.h>
#include <hip/hip_bf16.h>

// B=8, T=4096, C=1024, HS=64. Single attention head, causal, scale = C^-0.5.
// Pipeline: wprep (W -> Wt bf16 [192][1024]) ; proj (q,k bf16 [b][t][64], vT bf16 [b][64][t]) ;
//           flash (causal online-softmax attention, bf16 MFMA, fp32 out).

typedef __attribute__((ext_vector_type(8))) short short8;
typedef __attribute__((ext_vector_type(4))) float f32x4;

#define NB 8
#define NT 4096
#define NC 1024
#define NH 64

__device__ __forceinline__ unsigned short f2bf(float f) {
    unsigned int u = __builtin_bit_cast(unsigned int, f);
    u += 0x7fffu + ((u >> 16) & 1u);   // RNE
    return (unsigned short)(u >> 16);
}

// async global->LDS, 16B per lane; LDS dest = wave-uniform base + lane*16
#define GLOAD16(gp, lp)                                                        \
    __builtin_amdgcn_global_load_lds(                                          \
        (const __attribute__((address_space(1))) void*)(gp),                   \
        (__attribute__((address_space(3))) void*)(lp), 16, 0, 0)

// ---------------- W prep: Wt[n][c] = W_{n/64}[c][n%64] as bf16 -----------------
__global__ __launch_bounds__(256) void wprep_kernel(
    const float* __restrict__ Wk, const float* __restrict__ Wq,
    const float* __restrict__ Wv, unsigned short* __restrict__ Wt)
{
    int n = blockIdx.x;            // 0..191
    int which = n >> 6, h = n & 63;
    const float* W = (which == 0) ? Wk : (which == 1) ? Wq : Wv;
    for (int c = threadIdx.x; c < NC; c += 256)
        Wt[(size_t)n * NC + c] = f2bf(W[(size_t)c * NH + h]);
}

// ---------------- Projection GEMM: [32768 x 1024] @ [1024 x 192] ---------------
// m97-style 2-phase: double-buffered LDS, global_load_lds staging (width 16),
// BK=64. A tile [64 rows][64 k] fp32 (16 KB), B tile [192 n][64 k] bf16 (24 KB).
// Swizzle (rule #21): linear LDS dest, inverse-XOR on global src, XOR on ds_read.
//   A: 16B granule g ^= (row & 15)   (256 B rows, 16 granules)
//   B: 16B granule g ^= (row & 7)    (128 B rows,  8 granules)
__global__ __launch_bounds__(256, 2) void proj_kernel(
    const float* __restrict__ x, const unsigned short* __restrict__ Wt,
    unsigned short* __restrict__ qws, unsigned short* __restrict__ kws,
    unsigned short* __restrict__ vtws)
{
    __shared__ float          Albuf[2][64 * 64];           // 2 x 16 KB
    __shared__ unsigned short Blbuf[2][192 * 64];          // 2 x 24 KB

    const int lane = threadIdx.x & 63;
    const int wave = threadIdx.x >> 6;
    const int l15 = lane & 15;
    const int kg = lane >> 4;                  // 0..3
    const int m0 = blockIdx.x * 64;

    // ---- staging source pointers (pre-inverse-swizzled per lane) ----
    // A: 16 wave-instrs/block (4/wave); instr t=wave*4+i covers rows 4t..4t+3.
    //    lane l -> phys (row 4t+(l>>4), granule l&15); row&15 = 4i+(l>>4).
    const float* aSrc[4];
#pragma unroll
    for (int i = 0; i < 4; ++i) {
        int rlo = lane >> 4;
        int r = 4 * (wave * 4 + i) + rlo;
        int g = (lane & 15) ^ (4 * i + rlo);
        aSrc[i] = x + (size_t)(m0 + r) * NC + g * 4;
    }
    // B: 24 wave-instrs/block (6/wave); instr u=wave*6+i covers rows 8u..8u+7.
    //    lane l -> phys (row 8u+(l>>3), granule l&7); row&7 = l>>3.
    const unsigned short* bSrc[6];
#pragma unroll
    for (int i = 0; i < 6; ++i) {
        int r = 8 * (wave * 6 + i) + (lane >> 3);
        int g = (lane & 7) ^ (lane >> 3);
        bSrc[i] = Wt + (size_t)r * NC + g * 8;
    }

    f32x4 acc[12];
#pragma unroll
    for (int i = 0; i < 12; ++i) acc[i] = f32x4{0.f, 0.f, 0.f, 0.f};

    // stage chunk 0 into buf 0
#pragma unroll
    for (int i = 0; i < 4; ++i)
        GLOAD16(aSrc[i], (char*)&Albuf[0][0] + (wave * 4 + i) * 1024);
#pragma unroll
    for (int i = 0; i < 6; ++i)
        GLOAD16(bSrc[i], (char*)&Blbuf[0][0] + (wave * 6 + i) * 1024);
    __syncthreads();

    int buf = 0;
    for (int kc = 0; kc < 16; ++kc) {
        if (kc < 15) {   // issue async stage of next chunk into other buffer
#pragma unroll
            for (int i = 0; i < 4; ++i)
                GLOAD16(aSrc[i] + (kc + 1) * 64,
                        (char*)&Albuf[buf ^ 1][0] + (wave * 4 + i) * 1024);
#pragma unroll
            for (int i = 0; i < 6; ++i)
                GLOAD16(bSrc[i] + (kc + 1) * 64,
                        (char*)&Blbuf[buf ^ 1][0] + (wave * 6 + i) * 1024);
        }

        const char* Ab = (const char*)&Albuf[buf][0];
        const char* Bb = (const char*)&Blbuf[buf][0];
#pragma unroll
        for (int sub = 0; sub < 2; ++sub) {
            const int r = wave * 16 + l15;
            const int g0 = sub * 8 + kg * 2;
            f32x4 a0 = *(const f32x4*)(Ab + r * 256 + ((g0 ^ l15) * 16));
            f32x4 a1 = *(const f32x4*)(Ab + r * 256 + (((g0 + 1) ^ l15) * 16));
            short8 a;
            a[0] = (short)f2bf(a0[0]); a[1] = (short)f2bf(a0[1]);
            a[2] = (short)f2bf(a0[2]); a[3] = (short)f2bf(a0[3]);
            a[4] = (short)f2bf(a1[0]); a[5] = (short)f2bf(a1[1]);
            a[6] = (short)f2bf(a1[2]); a[7] = (short)f2bf(a1[3]);
#pragma unroll
            for (int nt = 0; nt < 12; ++nt) {
                int rb = nt * 16 + l15;
                short8 bfrag = *(const short8*)(
                    Bb + rb * 128 + ((((sub << 2) + kg) ^ (l15 & 7)) * 16));
                acc[nt] = __builtin_amdgcn_mfma_f32_16x16x32_bf16(a, bfrag, acc[nt], 0, 0, 0);
            }
        }
        __syncthreads();   // drains vmcnt (stage done) + lgkmcnt (reads done)
        buf ^= 1;
    }

    // C/D layout: col = lane&15, row = (lane>>4)*4 + reg  [HW-verified]
    const int crow0 = m0 + wave * 16 + (kg << 2);
#pragma unroll
    for (int nt = 0; nt < 12; ++nt) {
        int n = nt * 16 + l15;
        int which = n >> 6;
        int h = n & 63;
#pragma unroll
        for (int r = 0; r < 4; ++r) {
            int gm = crow0 + r;
            unsigned short v = f2bf(acc[nt][r]);
            if (which == 0) {
                kws[(size_t)gm * NH + h] = v;
            } else if (which == 1) {
                qws[(size_t)gm * NH + h] = v;
            } else {
                int bb = gm >> 12, tt = gm & 4095;
                vtws[((size_t)(bb * NH + h)) * NT + tt] = v;
            }
        }
    }
}

// ---------------- Flash attention (causal) -------------------------------------
// 512 blocks (8 batches x 64 q-tiles of 64 rows), 4 waves x 16 q-rows each.
// KV tiles of 64 keys. K tile [64 keys][64 d], V tile stored transposed [64 d][64 keys].
// All LDS tiles XOR-swizzled: byte ^= (row&7)<<4 (rows are 128B).
__global__ __launch_bounds__(256) void flash_kernel(
    const unsigned short* __restrict__ qws, const unsigned short* __restrict__ kws,
    const unsigned short* __restrict__ vtws, float* __restrict__ out)
{
    __shared__ unsigned short Klds[64 * 64];
    __shared__ unsigned short Vlds[64 * 64];
    __shared__ unsigned short Plds[4 * 16 * 64];   // per-wave 16x64 P strips

    const int id = blockIdx.x;
    const int b = id & 7;
    const int qt = 63 - (id >> 3);   // heavy tiles first for load balance
    const int lane = threadIdx.x & 63;
    const int wave = threadIdx.x >> 6;
    const int l15 = lane & 15;
    const int kg = lane >> 4;

    // Q fragments, kept in registers for the whole block
    short8 qf[2];
    {
        const unsigned short* qp =
            qws + ((size_t)(b * NT + qt * 64 + wave * 16 + l15)) * NH + kg * 8;
        qf[0] = *(const short8*)(qp);
        qf[1] = *(const short8*)(qp + 32);
    }

    f32x4 o[4];
#pragma unroll
    for (int dt = 0; dt < 4; ++dt) o[dt] = f32x4{0.f, 0.f, 0.f, 0.f};
    float m_r[4], l_r[4];
#pragma unroll
    for (int r = 0; r < 4; ++r) { m_r[r] = -INFINITY; l_r[r] = 0.f; }

    // staging assignment: thread -> (row 0..63, seg 0..3 of 32B)
    const int stg_row = threadIdx.x >> 2;
    const int stg_seg = threadIdx.x & 3;
    const unsigned short* kbase =
        kws + ((size_t)(b * NT) + stg_row) * NH + stg_seg * 16;
    const unsigned short* vbase =
        vtws + ((size_t)(b * NH + stg_row)) * NT + stg_seg * 16;
    const int sc0 = (stg_seg * 32) ^ ((stg_row & 7) << 4);
    const int sc1 = (stg_seg * 32 + 16) ^ ((stg_row & 7) << 4);
    char* kdst = (char*)Klds + stg_row * 128;
    char* vdst = (char*)Vlds + stg_row * 128;
    char* pw = (char*)Plds + wave * 2048;

    const float cs = 0.04508422f;   // log2(e) / 32

    for (int kv = 0; kv <= qt; ++kv) {
        __syncthreads();            // previous iter's LDS reads done
        {
            const uint4* kg4 = (const uint4*)(kbase + (size_t)kv * 64 * NH);
            uint4 k0 = kg4[0], k1 = kg4[1];
            const uint4* vg4 = (const uint4*)(vbase + kv * 64);
            uint4 v0 = vg4[0], v1 = vg4[1];
            *(uint4*)(kdst + sc0) = k0;
            *(uint4*)(kdst + sc1) = k1;
            *(uint4*)(vdst + sc0) = v0;
            *(uint4*)(vdst + sc1) = v1;
        }
        __syncthreads();

        // S = Q K^T  (wave strip: 16 q-rows x 64 keys)
        f32x4 s[4];
#pragma unroll
        for (int jt = 0; jt < 4; ++jt) s[jt] = f32x4{0.f, 0.f, 0.f, 0.f};
#pragma unroll
        for (int ks = 0; ks < 2; ++ks) {
            const int cbb = ks * 64 + kg * 16;
#pragma unroll
            for (int jt = 0; jt < 4; ++jt) {
                int krow = jt * 16 + l15;
                short8 kf = *(const short8*)((char*)Klds + krow * 128 +
                                             (cbb ^ ((krow & 7) << 4)));
                s[jt] = __builtin_amdgcn_mfma_f32_16x16x32_bf16(qf[ks], kf, s[jt], 0, 0, 0);
            }
        }

        // scale to log2 domain + causal mask (only diagonal tile needs masking)
        const bool diag = (kv == qt);
#pragma unroll
        for (int jt = 0; jt < 4; ++jt) {
            int jl = jt * 16 + l15;
#pragma unroll
            for (int r = 0; r < 4; ++r) {
                float v = s[jt][r] * cs;
                int il = (kg << 2) + r;
                if (diag && (jl > wave * 16 + il)) v = -1e30f;
                s[jt][r] = v;
            }
        }

        // row max over 64 keys: 4 jt-tiles then 16-lane butterfly
        float pmax[4];
#pragma unroll
        for (int r = 0; r < 4; ++r)
            pmax[r] = fmaxf(fmaxf(s[0][r], s[1][r]), fmaxf(s[2][r], s[3][r]));
#pragma unroll
        for (int off = 1; off < 16; off <<= 1)
#pragma unroll
            for (int r = 0; r < 4; ++r)
                pmax[r] = fmaxf(pmax[r], __shfl_xor(pmax[r], off));

        float alpha[4];
#pragma unroll
        for (int r = 0; r < 4; ++r) {
            float mn = fmaxf(m_r[r], pmax[r]);
            alpha[r] = exp2f(m_r[r] - mn);
            m_r[r] = mn;
        }

        // P = exp2(S - m), row sums
        float psum[4];
#pragma unroll
        for (int jt = 0; jt < 4; ++jt)
#pragma unroll
            for (int r = 0; r < 4; ++r)
                s[jt][r] = exp2f(s[jt][r] - m_r[r]);
#pragma unroll
        for (int r = 0; r < 4; ++r)
            psum[r] = (s[0][r] + s[1][r]) + (s[2][r] + s[3][r]);
#pragma unroll
        for (int off = 1; off < 16; off <<= 1)
#pragma unroll
            for (int r = 0; r < 4; ++r)
                psum[r] += __shfl_xor(psum[r], off);
#pragma unroll
        for (int r = 0; r < 4; ++r)
            l_r[r] = l_r[r] * alpha[r] + psum[r];
#pragma unroll
        for (int dt = 0; dt < 4; ++dt)
#pragma unroll
            for (int r = 0; r < 4; ++r)
                o[dt][r] *= alpha[r];

        // P (C-layout) -> LDS bf16, swizzled to match A-frag reads
#pragma unroll
        for (int jt = 0; jt < 4; ++jt) {
            int jl = jt * 16 + l15;
#pragma unroll
            for (int r = 0; r < 4; ++r) {
                int ir = (kg << 2) + r;
                *(unsigned short*)(pw + ir * 128 + ((jl * 2) ^ ((ir & 7) << 4))) =
                    f2bf(s[jt][r]);
            }
        }
        __syncthreads();   // intra-wave LDS write->read ordering (uniform barrier)

        // O += P @ V   (A = P strip, B = V^T rows)
#pragma unroll
        for (int ks = 0; ks < 2; ++ks) {
            const int cbb = ks * 64 + kg * 16;
            short8 pf = *(const short8*)(pw + l15 * 128 + (cbb ^ ((l15 & 7) << 4)));
#pragma unroll
            for (int dt = 0; dt < 4; ++dt) {
                int vrow = dt * 16 + l15;
                short8 vf = *(const short8*)((char*)Vlds + vrow * 128 +
                                             (cbb ^ ((vrow & 7) << 4)));
                o[dt] = __builtin_amdgcn_mfma_f32_16x16x32_bf16(pf, vf, o[dt], 0, 0, 0);
            }
        }
    }

    // epilogue: normalize and store fp32
    float linv[4];
#pragma unroll
    for (int r = 0; r < 4; ++r) linv[r] = 1.0f / l_r[r];
    size_t obase = ((size_t)b * NT + (size_t)qt * 64 + wave * 16 + (kg << 2)) * NH;
#pragma unroll
    for (int dt = 0; dt < 4; ++dt)
#pragma unroll
        for (int r = 0; r < 4; ++r)
            out[obase + (size_t)r * NH + dt * 16 + l15] = o[dt][r] * linv[r];
}

extern "C" void kernel_launch(void* const* d_in, const int* in_sizes, int n_in,
                              void* d_out, int out_size, void* d_ws, size_t ws_size,
                              hipStream_t stream) {
    const float* x  = (const float*)d_in[0];
    const float* Wk = (const float*)d_in[1];
    const float* Wq = (const float*)d_in[2];
    const float* Wv = (const float*)d_in[3];
    float* out = (float*)d_out;

    unsigned short* ws   = (unsigned short*)d_ws;
    const size_t qkv_elems = (size_t)NB * NT * NH;   // 2M elements each
    unsigned short* qws  = ws;
    unsigned short* kws  = qws + qkv_elems;
    unsigned short* vtws = kws + qkv_elems;
    unsigned short* Wt   = vtws + qkv_elems;          // 192*1024 bf16

    wprep_kernel<<<dim3(192), dim3(256), 0, stream>>>(Wk, Wq, Wv, Wt);
    proj_kernel<<<dim3(512), dim3(256), 0, stream>>>(x, Wt, qws, kws, vtws);
    flash_kernel<<<dim3(512), dim3(256), 0, stream>>>(qws, kws, vtws, out);
}

// Round 4
// 126.144 us; speedup vs baseline: 1.9718x; 1.2776x over previous
//
#include <hip/hip_runtime.h>
#include <hip/hip_bf16.h>

// B=8, T=4096, C=1024, HS=64. Single attention head, causal, scale = C^-0.5.
// Pipeline: wprep (W -> Wt bf16 [192][1024]) ; proj (q,k bf16 [b][t][64], vT bf16 [b][64][t]) ;
//           flash (causal online-softmax attention, swapped-operand MFMA, fp32 out).

typedef __attribute__((ext_vector_type(8))) short short8;
typedef __attribute__((ext_vector_type(4))) float f32x4;

#define NB 8
#define NT 4096
#define NC 1024
#define NH 64

__device__ __forceinline__ unsigned short f2bf(float f) {
    unsigned int u = __builtin_bit_cast(unsigned int, f);
    u += 0x7fffu + ((u >> 16) & 1u);   // RNE
    return (unsigned short)(u >> 16);
}

__device__ __forceinline__ unsigned cvt_pk_bf16(float lo, float hi) {
    unsigned r;
    asm("v_cvt_pk_bf16_f32 %0, %1, %2" : "=v"(r) : "v"(lo), "v"(hi));
    return r;
}

// async global->LDS, 16B per lane; LDS dest = wave-uniform base + lane*16
#define GLOAD16(gp, lp)                                                        \
    __builtin_amdgcn_global_load_lds(                                          \
        (const __attribute__((address_space(1))) void*)(gp),                   \
        (__attribute__((address_space(3))) void*)(lp), 16, 0, 0)

// ---------------- W prep: Wt[n][c] = W_{n/64}[c][n%64] as bf16 -----------------
__global__ __launch_bounds__(256) void wprep_kernel(
    const float* __restrict__ Wk, const float* __restrict__ Wq,
    const float* __restrict__ Wv, unsigned short* __restrict__ Wt)
{
    int n = blockIdx.x;            // 0..191
    int which = n >> 6, h = n & 63;
    const float* W = (which == 0) ? Wk : (which == 1) ? Wq : Wv;
    for (int c = threadIdx.x; c < NC; c += 256)
        Wt[(size_t)n * NC + c] = f2bf(W[(size_t)c * NH + h]);
}

// ---------------- Projection GEMM: [32768 x 1024] @ [1024 x 192] ---------------
// m97-style 2-phase: double-buffered LDS, global_load_lds staging (width 16),
// BK=64. A tile [64 rows][64 k] fp32 (16 KB), B tile [192 n][64 k] bf16 (24 KB).
// Swizzle (rule #21): linear LDS dest, inverse-XOR on global src, XOR on ds_read.
__global__ __launch_bounds__(256, 2) void proj_kernel(
    const float* __restrict__ x, const unsigned short* __restrict__ Wt,
    unsigned short* __restrict__ qws, unsigned short* __restrict__ kws,
    unsigned short* __restrict__ vtws)
{
    __shared__ float          Albuf[2][64 * 64];           // 2 x 16 KB
    __shared__ unsigned short Blbuf[2][192 * 64];          // 2 x 24 KB

    const int lane = threadIdx.x & 63;
    const int wave = threadIdx.x >> 6;
    const int l15 = lane & 15;
    const int kg = lane >> 4;                  // 0..3
    const int m0 = blockIdx.x * 64;

    const float* aSrc[4];
#pragma unroll
    for (int i = 0; i < 4; ++i) {
        int rlo = lane >> 4;
        int r = 4 * (wave * 4 + i) + rlo;
        int g = (lane & 15) ^ (4 * i + rlo);
        aSrc[i] = x + (size_t)(m0 + r) * NC + g * 4;
    }
    const unsigned short* bSrc[6];
#pragma unroll
    for (int i = 0; i < 6; ++i) {
        int r = 8 * (wave * 6 + i) + (lane >> 3);
        int g = (lane & 7) ^ (lane >> 3);
        bSrc[i] = Wt + (size_t)r * NC + g * 8;
    }

    f32x4 acc[12];
#pragma unroll
    for (int i = 0; i < 12; ++i) acc[i] = f32x4{0.f, 0.f, 0.f, 0.f};

#pragma unroll
    for (int i = 0; i < 4; ++i)
        GLOAD16(aSrc[i], (char*)&Albuf[0][0] + (wave * 4 + i) * 1024);
#pragma unroll
    for (int i = 0; i < 6; ++i)
        GLOAD16(bSrc[i], (char*)&Blbuf[0][0] + (wave * 6 + i) * 1024);
    __syncthreads();

    int buf = 0;
    for (int kc = 0; kc < 16; ++kc) {
        if (kc < 15) {
#pragma unroll
            for (int i = 0; i < 4; ++i)
                GLOAD16(aSrc[i] + (kc + 1) * 64,
                        (char*)&Albuf[buf ^ 1][0] + (wave * 4 + i) * 1024);
#pragma unroll
            for (int i = 0; i < 6; ++i)
                GLOAD16(bSrc[i] + (kc + 1) * 64,
                        (char*)&Blbuf[buf ^ 1][0] + (wave * 6 + i) * 1024);
        }

        const char* Ab = (const char*)&Albuf[buf][0];
        const char* Bb = (const char*)&Blbuf[buf][0];
#pragma unroll
        for (int sub = 0; sub < 2; ++sub) {
            const int r = wave * 16 + l15;
            const int g0 = sub * 8 + kg * 2;
            f32x4 a0 = *(const f32x4*)(Ab + r * 256 + ((g0 ^ l15) * 16));
            f32x4 a1 = *(const f32x4*)(Ab + r * 256 + (((g0 + 1) ^ l15) * 16));
            short8 a;
            a[0] = (short)f2bf(a0[0]); a[1] = (short)f2bf(a0[1]);
            a[2] = (short)f2bf(a0[2]); a[3] = (short)f2bf(a0[3]);
            a[4] = (short)f2bf(a1[0]); a[5] = (short)f2bf(a1[1]);
            a[6] = (short)f2bf(a1[2]); a[7] = (short)f2bf(a1[3]);
#pragma unroll
            for (int nt = 0; nt < 12; ++nt) {
                int rb = nt * 16 + l15;
                short8 bfrag = *(const short8*)(
                    Bb + rb * 128 + ((((sub << 2) + kg) ^ (l15 & 7)) * 16));
                acc[nt] = __builtin_amdgcn_mfma_f32_16x16x32_bf16(a, bfrag, acc[nt], 0, 0, 0);
            }
        }
        __syncthreads();
        buf ^= 1;
    }

    const int crow0 = m0 + wave * 16 + (kg << 2);
#pragma unroll
    for (int nt = 0; nt < 12; ++nt) {
        int n = nt * 16 + l15;
        int which = n >> 6;
        int h = n & 63;
#pragma unroll
        for (int r = 0; r < 4; ++r) {
            int gm = crow0 + r;
            unsigned short v = f2bf(acc[nt][r]);
            if (which == 0) {
                kws[(size_t)gm * NH + h] = v;
            } else if (which == 1) {
                qws[(size_t)gm * NH + h] = v;
            } else {
                int bb = gm >> 12, tt = gm & 4095;
                vtws[((size_t)(bb * NH + h)) * NT + tt] = v;
            }
        }
    }
}

// ---------------- Flash attention (causal, swapped operands) -------------------
// 512 blocks (8 batches x 64 q-tiles of 64 rows), 4 waves x 16 q-rows each.
// QK^T computed as mfma(K,Q) -> S^T (col=q=lane&15): softmax is lane-local.
// PV computed as mfma(V^T, P^T) -> O^T (col=q): rescale/epilogue lane-local.
// K/V double-buffered in LDS; next tile's global loads issued before compute.
__global__ __launch_bounds__(256) void flash_kernel(
    const unsigned short* __restrict__ qws, const unsigned short* __restrict__ kws,
    const unsigned short* __restrict__ vtws, float* __restrict__ out)
{
    __shared__ unsigned short Kbuf[2][64 * 64];
    __shared__ unsigned short Vbuf[2][64 * 64];
    __shared__ unsigned short Plds[4 * 16 * 64];   // per-wave 16x64 P strips

    const int id = blockIdx.x;
    const int b = id & 7;
    const int qt = 63 - (id >> 3);   // heavy tiles first for load balance
    const int lane = threadIdx.x & 63;
    const int wave = threadIdx.x >> 6;
    const int l15 = lane & 15;
    const int kg = lane >> 4;

    // Q fragments (kept in registers): lane holds Q[q = l15][d = kg*8 + j]
    short8 qf[2];
    {
        const unsigned short* qp =
            qws + ((size_t)(b * NT + qt * 64 + wave * 16 + l15)) * NH + kg * 8;
        qf[0] = *(const short8*)(qp);
        qf[1] = *(const short8*)(qp + 32);
    }

    f32x4 o[4];        // O^T: o[dt][r] = O[q=l15][d = dt*16 + kg*4 + r]
#pragma unroll
    for (int dt = 0; dt < 4; ++dt) o[dt] = f32x4{0.f, 0.f, 0.f, 0.f};
    float m_r = -INFINITY, l_r = 0.f;   // per-lane (q = l15)

    // staging assignment: thread -> (row 0..63, seg 0..3 of 32B)
    const int stg_row = threadIdx.x >> 2;
    const int stg_seg = threadIdx.x & 3;
    const unsigned short* kbase =
        kws + ((size_t)(b * NT) + stg_row) * NH + stg_seg * 16;
    const unsigned short* vbase =
        vtws + ((size_t)(b * NH + stg_row)) * NT + stg_seg * 16;
    const int sc0 = (stg_seg * 32) ^ ((stg_row & 7) << 4);
    const int sc1 = (stg_seg * 32 + 16) ^ ((stg_row & 7) << 4);
    char* pw = (char*)Plds + wave * 2048;
    const int pswz = (l15 & 7) << 4;

    const float cs = 0.04508422f;   // log2(e) / 32

    // prologue: stage tile 0 into buf 0
    {
        const uint4* kp = (const uint4*)(kbase);
        uint4 k0 = kp[0], k1 = kp[1];
        const uint4* vp = (const uint4*)(vbase);
        uint4 v0 = vp[0], v1 = vp[1];
        char* kd = (char*)Kbuf[0] + stg_row * 128;
        char* vd = (char*)Vbuf[0] + stg_row * 128;
        *(uint4*)(kd + sc0) = k0; *(uint4*)(kd + sc1) = k1;
        *(uint4*)(vd + sc0) = v0; *(uint4*)(vd + sc1) = v1;
    }
    __syncthreads();

    int cur = 0;
    for (int kv = 0; kv <= qt; ++kv) {
        // issue next tile's global loads early (hidden under compute)
        uint4 kn0, kn1, vn0, vn1;
        const bool pre = (kv < qt);
        if (pre) {
            const uint4* kp = (const uint4*)(kbase + (size_t)(kv + 1) * 64 * NH);
            kn0 = kp[0]; kn1 = kp[1];
            const uint4* vp = (const uint4*)(vbase + (size_t)(kv + 1) * 64);
            vn0 = vp[0]; vn1 = vp[1];
        }

        const char* Kb = (const char*)Kbuf[cur];
        const char* Vb = (const char*)Vbuf[cur];

        // S^T = mfma(K, Q): st[jt][r] = S[q=l15][key = jt*16 + kg*4 + r]
        f32x4 st[4];
#pragma unroll
        for (int jt = 0; jt < 4; ++jt) st[jt] = f32x4{0.f, 0.f, 0.f, 0.f};
#pragma unroll
        for (int ks = 0; ks < 2; ++ks) {
            const int cbb = ks * 64 + kg * 16;
#pragma unroll
            for (int jt = 0; jt < 4; ++jt) {
                int krow = jt * 16 + l15;
                short8 kf = *(const short8*)(Kb + krow * 128 +
                                             (cbb ^ ((krow & 7) << 4)));
                st[jt] = __builtin_amdgcn_mfma_f32_16x16x32_bf16(kf, qf[ks], st[jt], 0, 0, 0);
            }
        }

        // scale (log2 domain) + causal mask (diagonal tile only)
        const bool diag = (kv == qt);
#pragma unroll
        for (int jt = 0; jt < 4; ++jt)
#pragma unroll
            for (int r = 0; r < 4; ++r) {
                float v = st[jt][r] * cs;
                if (diag && (jt * 16 + (kg << 2) + r > wave * 16 + l15)) v = -1e30f;
                st[jt][r] = v;
            }

        // row max: in-register tree (16 values) + 2 shfl_xor across kg groups
        float pmax;
        {
            float t0 = fmaxf(fmaxf(st[0][0], st[0][1]), fmaxf(st[0][2], st[0][3]));
            float t1 = fmaxf(fmaxf(st[1][0], st[1][1]), fmaxf(st[1][2], st[1][3]));
            float t2 = fmaxf(fmaxf(st[2][0], st[2][1]), fmaxf(st[2][2], st[2][3]));
            float t3 = fmaxf(fmaxf(st[3][0], st[3][1]), fmaxf(st[3][2], st[3][3]));
            pmax = fmaxf(fmaxf(t0, t1), fmaxf(t2, t3));
        }
        pmax = fmaxf(pmax, __shfl_xor(pmax, 16));
        pmax = fmaxf(pmax, __shfl_xor(pmax, 32));

        float mn = fmaxf(m_r, pmax);
        float alpha = __builtin_amdgcn_exp2f(m_r - mn);
        m_r = mn;

        // P = exp2(S - m)
#pragma unroll
        for (int jt = 0; jt < 4; ++jt)
#pragma unroll
            for (int r = 0; r < 4; ++r)
                st[jt][r] = __builtin_amdgcn_exp2f(st[jt][r] - mn);

        // row sum: tree + 2 shfl_xor
        float ps;
        {
            float t0 = (st[0][0] + st[0][1]) + (st[0][2] + st[0][3]);
            float t1 = (st[1][0] + st[1][1]) + (st[1][2] + st[1][3]);
            float t2 = (st[2][0] + st[2][1]) + (st[2][2] + st[2][3]);
            float t3 = (st[3][0] + st[3][1]) + (st[3][2] + st[3][3]);
            ps = (t0 + t1) + (t2 + t3);
        }
        ps += __shfl_xor(ps, 16);
        ps += __shfl_xor(ps, 32);

        l_r = l_r * alpha + ps;
#pragma unroll
        for (int dt = 0; dt < 4; ++dt)
#pragma unroll
            for (int r = 0; r < 4; ++r)
                o[dt][r] *= alpha;

        // pack P to bf16 and write per-wave strip: row q=l15, keys jt*16+kg*4+r
#pragma unroll
        for (int jt = 0; jt < 4; ++jt) {
            unsigned w0 = cvt_pk_bf16(st[jt][0], st[jt][1]);
            unsigned w1 = cvt_pk_bf16(st[jt][2], st[jt][3]);
            uint2 t; t.x = w0; t.y = w1;
            *(uint2*)(pw + l15 * 128 + ((jt * 32 + kg * 8) ^ pswz)) = t;
        }
        // read P^T B-frags: lane holds P[q=l15][keys ks*32 + kg*8 .. +7]
        short8 pf[2];
#pragma unroll
        for (int ks = 0; ks < 2; ++ks)
            pf[ks] = *(const short8*)(pw + l15 * 128 + ((ks * 64 + kg * 16) ^ pswz));

        // O^T += mfma(V^T, P^T)
#pragma unroll
        for (int ks = 0; ks < 2; ++ks) {
            const int cbb = ks * 64 + kg * 16;
#pragma unroll
            for (int dt = 0; dt < 4; ++dt) {
                int vrow = dt * 16 + l15;
                short8 vf = *(const short8*)(Vb + vrow * 128 +
                                             (cbb ^ ((vrow & 7) << 4)));
                o[dt] = __builtin_amdgcn_mfma_f32_16x16x32_bf16(vf, pf[ks], o[dt], 0, 0, 0);
            }
        }

        if (pre) {
            __syncthreads();   // all waves done reading buf[cur^1]
            char* kd = (char*)Kbuf[cur ^ 1] + stg_row * 128;
            char* vd = (char*)Vbuf[cur ^ 1] + stg_row * 128;
            *(uint4*)(kd + sc0) = kn0; *(uint4*)(kd + sc1) = kn1;
            *(uint4*)(vd + sc0) = vn0; *(uint4*)(vd + sc1) = vn1;
            __syncthreads();   // writes visible
            cur ^= 1;
        }
    }

    // epilogue: normalize and store fp32 (lane-local q = l15)
    float linv = __builtin_amdgcn_rcpf(l_r);
    size_t obase = ((size_t)b * NT + (size_t)qt * 64 + wave * 16 + l15) * NH + (kg << 2);
#pragma unroll
    for (int dt = 0; dt < 4; ++dt) {
        f32x4 v = o[dt];
        v[0] *= linv; v[1] *= linv; v[2] *= linv; v[3] *= linv;
        *(f32x4*)(out + obase + dt * 16) = v;
    }
}

extern "C" void kernel_launch(void* const* d_in, const int* in_sizes, int n_in,
                              void* d_out, int out_size, void* d_ws, size_t ws_size,
                              hipStream_t stream) {
    const float* x  = (const float*)d_in[0];
    const float* Wk = (const float*)d_in[1];
    const float* Wq = (const float*)d_in[2];
    const float* Wv = (const float*)d_in[3];
    float* out = (float*)d_out;

    unsigned short* ws   = (unsigned short*)d_ws;
    const size_t qkv_elems = (size_t)NB * NT * NH;   // 2M elements each
    unsigned short* qws  = ws;
    unsigned short* kws  = qws + qkv_elems;
    unsigned short* vtws = kws + qkv_elems;
    unsigned short* Wt   = vtws + qkv_elems;          // 192*1024 bf16

    wprep_kernel<<<dim3(192), dim3(256), 0, stream>>>(Wk, Wq, Wv, Wt);
    proj_kernel<<<dim3(512), dim3(256), 0, stream>>>(x, Wt, qws, kws, vtws);
    flash_kernel<<<dim3(512), dim3(256), 0, stream>>>(qws, kws, vtws, out);
}

// Round 5
// 102.213 us; speedup vs baseline: 2.4334x; 1.2341x over previous
//
#include <hip/hip_runtime.h>
#include <hip/hip_bf16.h>

// B=8, T=4096, C=1024, HS=64. Single attention head, causal, scale = C^-0.5.
// Pipeline: wprep (W -> Wt bf16 [192][1024]) ; proj (q,k bf16 [b][t][64], vT bf16 [b][64][t]) ;
//           flash (causal online-softmax attention, swapped-operand MFMA, fp32 out).
// Q is pre-scaled by log2(e)/32 in proj, so QK^T is directly log2-domain.

typedef __attribute__((ext_vector_type(8))) short short8;
typedef __attribute__((ext_vector_type(4))) float f32x4;

#define NB 8
#define NT 4096
#define NC 1024
#define NH 64

__device__ __forceinline__ unsigned short f2bf(float f) {
    unsigned int u = __builtin_bit_cast(unsigned int, f);
    u += 0x7fffu + ((u >> 16) & 1u);   // RNE
    return (unsigned short)(u >> 16);
}

__device__ __forceinline__ unsigned cvt_pk_bf16(float lo, float hi) {
    unsigned r;
    asm("v_cvt_pk_bf16_f32 %0, %1, %2" : "=v"(r) : "v"(lo), "v"(hi));
    return r;
}

// async global->LDS, 16B per lane; LDS dest = wave-uniform base + lane*16
#define GLOAD16(gp, lp)                                                        \
    __builtin_amdgcn_global_load_lds(                                          \
        (const __attribute__((address_space(1))) void*)(gp),                   \
        (__attribute__((address_space(3))) void*)(lp), 16, 0, 0)

// ---------------- W prep: Wt[n][c] = W_{n/64}[c][n%64] as bf16 -----------------
__global__ __launch_bounds__(256) void wprep_kernel(
    const float* __restrict__ Wk, const float* __restrict__ Wq,
    const float* __restrict__ Wv, unsigned short* __restrict__ Wt)
{
    int n = blockIdx.x;            // 0..191
    int which = n >> 6, h = n & 63;
    const float* W = (which == 0) ? Wk : (which == 1) ? Wq : Wv;
    for (int c = threadIdx.x; c < NC; c += 256)
        Wt[(size_t)n * NC + c] = f2bf(W[(size_t)c * NH + h]);
}

// ---------------- Projection GEMM: [32768 x 1024] @ [1024 x 192] ---------------
// m97-style 2-phase: double-buffered LDS, global_load_lds staging (width 16),
// BK=64. A tile [64 rows][64 k] fp32 (16 KB), B tile [192 n][64 k] bf16 (24 KB).
// Swizzle (rule #21): linear LDS dest, inverse-XOR on global src, XOR on ds_read.
__global__ __launch_bounds__(256, 2) void proj_kernel(
    const float* __restrict__ x, const unsigned short* __restrict__ Wt,
    unsigned short* __restrict__ qws, unsigned short* __restrict__ kws,
    unsigned short* __restrict__ vtws)
{
    __shared__ float          Albuf[2][64 * 64];           // 2 x 16 KB
    __shared__ unsigned short Blbuf[2][192 * 64];          // 2 x 24 KB

    const int lane = threadIdx.x & 63;
    const int wave = threadIdx.x >> 6;
    const int l15 = lane & 15;
    const int kg = lane >> 4;                  // 0..3
    const int m0 = blockIdx.x * 64;

    const float* aSrc[4];
#pragma unroll
    for (int i = 0; i < 4; ++i) {
        int rlo = lane >> 4;
        int r = 4 * (wave * 4 + i) + rlo;
        int g = (lane & 15) ^ (4 * i + rlo);
        aSrc[i] = x + (size_t)(m0 + r) * NC + g * 4;
    }
    const unsigned short* bSrc[6];
#pragma unroll
    for (int i = 0; i < 6; ++i) {
        int r = 8 * (wave * 6 + i) + (lane >> 3);
        int g = (lane & 7) ^ (lane >> 3);
        bSrc[i] = Wt + (size_t)r * NC + g * 8;
    }

    f32x4 acc[12];
#pragma unroll
    for (int i = 0; i < 12; ++i) acc[i] = f32x4{0.f, 0.f, 0.f, 0.f};

#pragma unroll
    for (int i = 0; i < 4; ++i)
        GLOAD16(aSrc[i], (char*)&Albuf[0][0] + (wave * 4 + i) * 1024);
#pragma unroll
    for (int i = 0; i < 6; ++i)
        GLOAD16(bSrc[i], (char*)&Blbuf[0][0] + (wave * 6 + i) * 1024);
    __syncthreads();

    int buf = 0;
    for (int kc = 0; kc < 16; ++kc) {
        if (kc < 15) {
#pragma unroll
            for (int i = 0; i < 4; ++i)
                GLOAD16(aSrc[i] + (kc + 1) * 64,
                        (char*)&Albuf[buf ^ 1][0] + (wave * 4 + i) * 1024);
#pragma unroll
            for (int i = 0; i < 6; ++i)
                GLOAD16(bSrc[i] + (kc + 1) * 64,
                        (char*)&Blbuf[buf ^ 1][0] + (wave * 6 + i) * 1024);
        }

        const char* Ab = (const char*)&Albuf[buf][0];
        const char* Bb = (const char*)&Blbuf[buf][0];
#pragma unroll
        for (int sub = 0; sub < 2; ++sub) {
            const int r = wave * 16 + l15;
            const int g0 = sub * 8 + kg * 2;
            f32x4 a0 = *(const f32x4*)(Ab + r * 256 + ((g0 ^ l15) * 16));
            f32x4 a1 = *(const f32x4*)(Ab + r * 256 + (((g0 + 1) ^ l15) * 16));
            short8 a;
            a[0] = (short)f2bf(a0[0]); a[1] = (short)f2bf(a0[1]);
            a[2] = (short)f2bf(a0[2]); a[3] = (short)f2bf(a0[3]);
            a[4] = (short)f2bf(a1[0]); a[5] = (short)f2bf(a1[1]);
            a[6] = (short)f2bf(a1[2]); a[7] = (short)f2bf(a1[3]);
#pragma unroll
            for (int nt = 0; nt < 12; ++nt) {
                int rb = nt * 16 + l15;
                short8 bfrag = *(const short8*)(
                    Bb + rb * 128 + ((((sub << 2) + kg) ^ (l15 & 7)) * 16));
                acc[nt] = __builtin_amdgcn_mfma_f32_16x16x32_bf16(a, bfrag, acc[nt], 0, 0, 0);
            }
        }
        __syncthreads();
        buf ^= 1;
    }

    const float cs = 0.04508422f;   // log2(e) / 32  (folded into q)
    const int crow0 = m0 + wave * 16 + (kg << 2);
#pragma unroll
    for (int nt = 0; nt < 12; ++nt) {
        int n = nt * 16 + l15;
        int which = n >> 6;
        int h = n & 63;
#pragma unroll
        for (int r = 0; r < 4; ++r) {
            int gm = crow0 + r;
            float av = acc[nt][r];
            if (which == 1) av *= cs;
            unsigned short v = f2bf(av);
            if (which == 0) {
                kws[(size_t)gm * NH + h] = v;
            } else if (which == 1) {
                qws[(size_t)gm * NH + h] = v;
            } else {
                int bb = gm >> 12, tt = gm & 4095;
                vtws[((size_t)(bb * NH + h)) * NT + tt] = v;
            }
        }
    }
}

// ---------------- Flash attention (causal, swapped operands) -------------------
// 512 blocks, 4 waves x 16 q-rows each. Swapped MFMA: softmax lane-local.
// Defer-max (THR=8 log2 units) with lane-local check: common path has NO
// cross-lane ops; l kept as per-lane partial, reduced in epilogue.
// Balanced launch: blocks c and c+256 get q-tiles summing to 63.
__global__ __launch_bounds__(256) void flash_kernel(
    const unsigned short* __restrict__ qws, const unsigned short* __restrict__ kws,
    const unsigned short* __restrict__ vtws, float* __restrict__ out)
{
    __shared__ unsigned short Kbuf[2][64 * 64];
    __shared__ unsigned short Vbuf[2][64 * 64];
    __shared__ unsigned short Plds[4 * 16 * 64];   // per-wave 16x64 P strips

    const int id = blockIdx.x;
    const int half = id >> 8;          // 0: heavy half, 1: light half
    const int rem = id & 255;
    const int b = rem & 7;
    const int i32 = rem >> 3;          // 0..31
    const int qt = half ? i32 : (63 - i32);
    const int lane = threadIdx.x & 63;
    const int wave = threadIdx.x >> 6;
    const int l15 = lane & 15;
    const int kg = lane >> 4;

    // Q fragments (pre-scaled by log2(e)/32): lane holds Q[q=l15][d=kg*8+j]
    short8 qf[2];
    {
        const unsigned short* qp =
            qws + ((size_t)(b * NT + qt * 64 + wave * 16 + l15)) * NH + kg * 8;
        qf[0] = *(const short8*)(qp);
        qf[1] = *(const short8*)(qp + 32);
    }

    f32x4 o[4];        // O^T: o[dt][r] = O[q=l15][d = dt*16 + kg*4 + r]
#pragma unroll
    for (int dt = 0; dt < 4; ++dt) o[dt] = f32x4{0.f, 0.f, 0.f, 0.f};
    float m_r = -INFINITY;   // row max (uniform across the row's 4 kg-lanes)
    float l_r = 0.f;         // per-lane PARTIAL sum (own 16 keys)

    // staging assignment: thread -> (row 0..63, seg 0..3 of 32B)
    const int stg_row = threadIdx.x >> 2;
    const int stg_seg = threadIdx.x & 3;
    const unsigned short* kbase =
        kws + ((size_t)(b * NT) + stg_row) * NH + stg_seg * 16;
    const unsigned short* vbase =
        vtws + ((size_t)(b * NH + stg_row)) * NT + stg_seg * 16;
    const int sc0 = (stg_seg * 32) ^ ((stg_row & 7) << 4);
    const int sc1 = (stg_seg * 32 + 16) ^ ((stg_row & 7) << 4);
    char* pw = (char*)Plds + wave * 2048;
    const int pswz = (l15 & 7) << 4;

    // prologue: stage tile 0 into buf 0
    {
        const uint4* kp = (const uint4*)(kbase);
        uint4 k0 = kp[0], k1 = kp[1];
        const uint4* vp = (const uint4*)(vbase);
        uint4 v0 = vp[0], v1 = vp[1];
        char* kd = (char*)Kbuf[0] + stg_row * 128;
        char* vd = (char*)Vbuf[0] + stg_row * 128;
        *(uint4*)(kd + sc0) = k0; *(uint4*)(kd + sc1) = k1;
        *(uint4*)(vd + sc0) = v0; *(uint4*)(vd + sc1) = v1;
    }
    __syncthreads();

    int cur = 0;
    for (int kv = 0; kv <= qt; ++kv) {
        // issue next tile's global loads early (hidden under compute)
        uint4 kn0, kn1, vn0, vn1;
        const bool pre = (kv < qt);
        if (pre) {
            const uint4* kp = (const uint4*)(kbase + (size_t)(kv + 1) * 64 * NH);
            kn0 = kp[0]; kn1 = kp[1];
            const uint4* vp = (const uint4*)(vbase + (size_t)(kv + 1) * 64);
            vn0 = vp[0]; vn1 = vp[1];
        }

        const char* Kb = (const char*)Kbuf[cur];
        const char* Vb = (const char*)Vbuf[cur];

        // S^T = mfma(K, Q): st[jt][r] = S[q=l15][key = jt*16 + kg*4 + r]
        f32x4 st[4];
#pragma unroll
        for (int jt = 0; jt < 4; ++jt) st[jt] = f32x4{0.f, 0.f, 0.f, 0.f};
#pragma unroll
        for (int ks = 0; ks < 2; ++ks) {
            const int cbb = ks * 64 + kg * 16;
#pragma unroll
            for (int jt = 0; jt < 4; ++jt) {
                int krow = jt * 16 + l15;
                short8 kf = *(const short8*)(Kb + krow * 128 +
                                             (cbb ^ ((krow & 7) << 4)));
                st[jt] = __builtin_amdgcn_mfma_f32_16x16x32_bf16(kf, qf[ks], st[jt], 0, 0, 0);
            }
        }

        // causal mask: only the diagonal tile (uniform branch)
        if (kv == qt) {
#pragma unroll
            for (int jt = 0; jt < 4; ++jt)
#pragma unroll
                for (int r = 0; r < 4; ++r)
                    if (jt * 16 + (kg << 2) + r > wave * 16 + l15)
                        st[jt][r] = -1e30f;
        }

        // lane-local max over own 16 keys (no cross-lane)
        float lmax;
        {
            float t0 = fmaxf(fmaxf(st[0][0], st[0][1]), fmaxf(st[0][2], st[0][3]));
            float t1 = fmaxf(fmaxf(st[1][0], st[1][1]), fmaxf(st[1][2], st[1][3]));
            float t2 = fmaxf(fmaxf(st[2][0], st[2][1]), fmaxf(st[2][2], st[2][3]));
            float t3 = fmaxf(fmaxf(st[3][0], st[3][1]), fmaxf(st[3][2], st[3][3]));
            lmax = fmaxf(fmaxf(t0, t1), fmaxf(t2, t3));
        }

        // defer-max: rescale only when some row grew past m+8 (rare)
        if (!__all(lmax <= m_r + 8.0f)) {
            float pmax = lmax;
            pmax = fmaxf(pmax, __shfl_xor(pmax, 16));
            pmax = fmaxf(pmax, __shfl_xor(pmax, 32));
            float mn = fmaxf(m_r, pmax);
            float alpha = __builtin_amdgcn_exp2f(m_r - mn);
            m_r = mn;
            l_r *= alpha;
#pragma unroll
            for (int dt = 0; dt < 4; ++dt)
#pragma unroll
                for (int r = 0; r < 4; ++r)
                    o[dt][r] *= alpha;
        }

        // P = exp2(S - m), bounded by 2^8; accumulate per-lane partial l
#pragma unroll
        for (int jt = 0; jt < 4; ++jt)
#pragma unroll
            for (int r = 0; r < 4; ++r)
                st[jt][r] = __builtin_amdgcn_exp2f(st[jt][r] - m_r);
        {
            float t0 = (st[0][0] + st[0][1]) + (st[0][2] + st[0][3]);
            float t1 = (st[1][0] + st[1][1]) + (st[1][2] + st[1][3]);
            float t2 = (st[2][0] + st[2][1]) + (st[2][2] + st[2][3]);
            float t3 = (st[3][0] + st[3][1]) + (st[3][2] + st[3][3]);
            l_r += (t0 + t1) + (t2 + t3);
        }

        // pack P to bf16, per-wave LDS strip round-trip -> B-frag layout
#pragma unroll
        for (int jt = 0; jt < 4; ++jt) {
            unsigned w0 = cvt_pk_bf16(st[jt][0], st[jt][1]);
            unsigned w1 = cvt_pk_bf16(st[jt][2], st[jt][3]);
            uint2 t; t.x = w0; t.y = w1;
            *(uint2*)(pw + l15 * 128 + ((jt * 32 + kg * 8) ^ pswz)) = t;
        }
        short8 pf[2];
#pragma unroll
        for (int ks = 0; ks < 2; ++ks)
            pf[ks] = *(const short8*)(pw + l15 * 128 + ((ks * 64 + kg * 16) ^ pswz));

        // O^T += mfma(V^T, P^T)
#pragma unroll
        for (int ks = 0; ks < 2; ++ks) {
            const int cbb = ks * 64 + kg * 16;
#pragma unroll
            for (int dt = 0; dt < 4; ++dt) {
                int vrow = dt * 16 + l15;
                short8 vf = *(const short8*)(Vb + vrow * 128 +
                                             (cbb ^ ((vrow & 7) << 4)));
                o[dt] = __builtin_amdgcn_mfma_f32_16x16x32_bf16(vf, pf[ks], o[dt], 0, 0, 0);
            }
        }

        if (pre) {
            __syncthreads();   // all waves done reading buf[cur^1]
            char* kd = (char*)Kbuf[cur ^ 1] + stg_row * 128;
            char* vd = (char*)Vbuf[cur ^ 1] + stg_row * 128;
            *(uint4*)(kd + sc0) = kn0; *(uint4*)(kd + sc1) = kn1;
            *(uint4*)(vd + sc0) = vn0; *(uint4*)(vd + sc1) = vn1;
            __syncthreads();   // writes visible
            cur ^= 1;
        }
    }

    // epilogue: reduce partial l across the row's 4 kg-lanes, normalize, store
    float lsum = l_r;
    lsum += __shfl_xor(lsum, 16);
    lsum += __shfl_xor(lsum, 32);
    float linv = __builtin_amdgcn_rcpf(lsum);
    size_t obase = ((size_t)b * NT + (size_t)qt * 64 + wave * 16 + l15) * NH + (kg << 2);
#pragma unroll
    for (int dt = 0; dt < 4; ++dt) {
        f32x4 v = o[dt];
        v[0] *= linv; v[1] *= linv; v[2] *= linv; v[3] *= linv;
        *(f32x4*)(out + obase + dt * 16) = v;
    }
}

extern "C" void kernel_launch(void* const* d_in, const int* in_sizes, int n_in,
                              void* d_out, int out_size, void* d_ws, size_t ws_size,
                              hipStream_t stream) {
    const float* x  = (const float*)d_in[0];
    const float* Wk = (const float*)d_in[1];
    const float* Wq = (const float*)d_in[2];
    const float* Wv = (const float*)d_in[3];
    float* out = (float*)d_out;

    unsigned short* ws   = (unsigned short*)d_ws;
    const size_t qkv_elems = (size_t)NB * NT * NH;   // 2M elements each
    unsigned short* qws  = ws;
    unsigned short* kws  = qws + qkv_elems;
    unsigned short* vtws = kws + qkv_elems;
    unsigned short* Wt   = vtws + qkv_elems;          // 192*1024 bf16

    wprep_kernel<<<dim3(192), dim3(256), 0, stream>>>(Wk, Wq, Wv, Wt);
    proj_kernel<<<dim3(512), dim3(256), 0, stream>>>(x, Wt, qws, kws, vtws);
    flash_kernel<<<dim3(512), dim3(256), 0, stream>>>(qws, kws, vtws, out);
}

// Round 6
// 98.092 us; speedup vs baseline: 2.5357x; 1.0420x over previous
//
#include <hip/hip_runtime.h>
#include <hip/hip_bf16.h>

// B=8, T=4096, C=1024, HS=64. Single attention head, causal, scale = C^-0.5.
// Pipeline: wprep (W -> Wt bf16 [192][1024]) ; proj (q,k bf16 [b][t][64], vT bf16 [b][64][t]) ;
//           flash (split-KV causal online-softmax, swapped-operand MFMA, partial out) ;
//           combine (merge the two KV halves, normalize, fp32 out).
// Q is pre-scaled by log2(e)/32 in proj, so QK^T is directly log2-domain.

typedef __attribute__((ext_vector_type(8))) short short8;
typedef __attribute__((ext_vector_type(4))) float f32x4;

#define NB 8
#define NT 4096
#define NC 1024
#define NH 64

__device__ __forceinline__ unsigned short f2bf(float f) {
    unsigned int u = __builtin_bit_cast(unsigned int, f);
    u += 0x7fffu + ((u >> 16) & 1u);   // RNE
    return (unsigned short)(u >> 16);
}

__device__ __forceinline__ unsigned cvt_pk_bf16(float lo, float hi) {
    unsigned r;
    asm("v_cvt_pk_bf16_f32 %0, %1, %2" : "=v"(r) : "v"(lo), "v"(hi));
    return r;
}

// async global->LDS, 16B per lane; LDS dest = wave-uniform base + lane*16
#define GLOAD16(gp, lp)                                                        \
    __builtin_amdgcn_global_load_lds(                                          \
        (const __attribute__((address_space(1))) void*)(gp),                   \
        (__attribute__((address_space(3))) void*)(lp), 16, 0, 0)

// ---------------- W prep: Wt[n][c] = W_{n/64}[c][n%64] as bf16 -----------------
__global__ __launch_bounds__(256) void wprep_kernel(
    const float* __restrict__ Wk, const float* __restrict__ Wq,
    const float* __restrict__ Wv, unsigned short* __restrict__ Wt)
{
    int n = blockIdx.x;            // 0..191
    int which = n >> 6, h = n & 63;
    const float* W = (which == 0) ? Wk : (which == 1) ? Wq : Wv;
    for (int c = threadIdx.x; c < NC; c += 256)
        Wt[(size_t)n * NC + c] = f2bf(W[(size_t)c * NH + h]);
}

// ---------------- Projection GEMM: [32768 x 1024] @ [1024 x 192] ---------------
// m97-style 2-phase: double-buffered LDS, global_load_lds staging (width 16),
// BK=64. A tile [64 rows][64 k] fp32 (16 KB), B tile [192 n][64 k] bf16 (24 KB).
__global__ __launch_bounds__(256, 2) void proj_kernel(
    const float* __restrict__ x, const unsigned short* __restrict__ Wt,
    unsigned short* __restrict__ qws, unsigned short* __restrict__ kws,
    unsigned short* __restrict__ vtws)
{
    __shared__ float          Albuf[2][64 * 64];           // 2 x 16 KB
    __shared__ unsigned short Blbuf[2][192 * 64];          // 2 x 24 KB

    const int lane = threadIdx.x & 63;
    const int wave = threadIdx.x >> 6;
    const int l15 = lane & 15;
    const int kg = lane >> 4;                  // 0..3
    const int m0 = blockIdx.x * 64;

    const float* aSrc[4];
#pragma unroll
    for (int i = 0; i < 4; ++i) {
        int rlo = lane >> 4;
        int r = 4 * (wave * 4 + i) + rlo;
        int g = (lane & 15) ^ (4 * i + rlo);
        aSrc[i] = x + (size_t)(m0 + r) * NC + g * 4;
    }
    const unsigned short* bSrc[6];
#pragma unroll
    for (int i = 0; i < 6; ++i) {
        int r = 8 * (wave * 6 + i) + (lane >> 3);
        int g = (lane & 7) ^ (lane >> 3);
        bSrc[i] = Wt + (size_t)r * NC + g * 8;
    }

    f32x4 acc[12];
#pragma unroll
    for (int i = 0; i < 12; ++i) acc[i] = f32x4{0.f, 0.f, 0.f, 0.f};

#pragma unroll
    for (int i = 0; i < 4; ++i)
        GLOAD16(aSrc[i], (char*)&Albuf[0][0] + (wave * 4 + i) * 1024);
#pragma unroll
    for (int i = 0; i < 6; ++i)
        GLOAD16(bSrc[i], (char*)&Blbuf[0][0] + (wave * 6 + i) * 1024);
    __syncthreads();

    int buf = 0;
    for (int kc = 0; kc < 16; ++kc) {
        if (kc < 15) {
#pragma unroll
            for (int i = 0; i < 4; ++i)
                GLOAD16(aSrc[i] + (kc + 1) * 64,
                        (char*)&Albuf[buf ^ 1][0] + (wave * 4 + i) * 1024);
#pragma unroll
            for (int i = 0; i < 6; ++i)
                GLOAD16(bSrc[i] + (kc + 1) * 64,
                        (char*)&Blbuf[buf ^ 1][0] + (wave * 6 + i) * 1024);
        }

        const char* Ab = (const char*)&Albuf[buf][0];
        const char* Bb = (const char*)&Blbuf[buf][0];
#pragma unroll
        for (int sub = 0; sub < 2; ++sub) {
            const int r = wave * 16 + l15;
            const int g0 = sub * 8 + kg * 2;
            f32x4 a0 = *(const f32x4*)(Ab + r * 256 + ((g0 ^ l15) * 16));
            f32x4 a1 = *(const f32x4*)(Ab + r * 256 + (((g0 + 1) ^ l15) * 16));
            short8 a;
            a[0] = (short)f2bf(a0[0]); a[1] = (short)f2bf(a0[1]);
            a[2] = (short)f2bf(a0[2]); a[3] = (short)f2bf(a0[3]);
            a[4] = (short)f2bf(a1[0]); a[5] = (short)f2bf(a1[1]);
            a[6] = (short)f2bf(a1[2]); a[7] = (short)f2bf(a1[3]);
#pragma unroll
            for (int nt = 0; nt < 12; ++nt) {
                int rb = nt * 16 + l15;
                short8 bfrag = *(const short8*)(
                    Bb + rb * 128 + ((((sub << 2) + kg) ^ (l15 & 7)) * 16));
                acc[nt] = __builtin_amdgcn_mfma_f32_16x16x32_bf16(a, bfrag, acc[nt], 0, 0, 0);
            }
        }
        __syncthreads();
        buf ^= 1;
    }

    const float cs = 0.04508422f;   // log2(e) / 32  (folded into q)
    const int crow0 = m0 + wave * 16 + (kg << 2);
#pragma unroll
    for (int nt = 0; nt < 12; ++nt) {
        int n = nt * 16 + l15;
        int which = n >> 6;
        int h = n & 63;
#pragma unroll
        for (int r = 0; r < 4; ++r) {
            int gm = crow0 + r;
            float av = acc[nt][r];
            if (which == 1) av *= cs;
            unsigned short v = f2bf(av);
            if (which == 0) {
                kws[(size_t)gm * NH + h] = v;
            } else if (which == 1) {
                qws[(size_t)gm * NH + h] = v;
            } else {
                int bb = gm >> 12, tt = gm & 4095;
                vtws[((size_t)(bb * NH + h)) * NT + tt] = v;
            }
        }
    }
}

// ---------------- Flash attention (causal, swapped operands, split-KV) ---------
// 1024 blocks = 2 KV-halves x (8 batches x 64 q-tiles). 4 waves x 16 q-rows.
// Each block processes its KV sub-range and writes unnormalized partial O^T
// (fp32) plus per-row (m, l) to workspace. Heavy/light q-tiles paired so the
// per-CU work is ~constant. 40 KB LDS -> 4 blocks/CU = 16 waves/CU.
__global__ __launch_bounds__(256) void flash_kernel(
    const unsigned short* __restrict__ qws, const unsigned short* __restrict__ kws,
    const unsigned short* __restrict__ vtws,
    float* __restrict__ opart, float* __restrict__ mlpart)
{
    __shared__ unsigned short Kbuf[2][64 * 64];
    __shared__ unsigned short Vbuf[2][64 * 64];
    __shared__ unsigned short Plds[4 * 16 * 64];   // per-wave 16x64 P strips

    const int id = blockIdx.x;
    const int kvh = id >> 9;           // KV half: 0 = [0,h), 1 = [h,nkv)
    const int rem9 = id & 511;
    const int lighthalf = rem9 >> 8;   // 0: heavy q-tiles, 1: light
    const int rem = rem9 & 255;
    const int b = rem & 7;
    const int i32 = rem >> 3;          // 0..31
    const int qt = lighthalf ? i32 : (63 - i32);
    const int nkv = qt + 1;
    const int hsp = nkv - (nkv >> 1);  // ceil(nkv/2)
    const int k0 = kvh ? hsp : 0;
    const int k1 = kvh ? nkv : hsp;
    const int pid = (kvh << 9) | rem9 ? 0 : 0, pid_ = (kvh << 9) | ((b << 6) | qt);
    (void)pid;

    float* mlp = mlpart + (size_t)pid_ * 128;
    float* op  = opart + (size_t)pid_ * 4096;

    if (k0 >= k1) {                    // empty partition (qt=0, half B)
        f32x4 z = f32x4{0.f, 0.f, 0.f, 0.f};
        f32x4* op4 = (f32x4*)op;
        for (int i = threadIdx.x; i < 1024; i += 256) op4[i] = z;
        if (threadIdx.x < 64) {
            mlp[threadIdx.x] = -INFINITY;
            mlp[64 + threadIdx.x] = 0.f;
        }
        return;
    }

    const int lane = threadIdx.x & 63;
    const int wave = threadIdx.x >> 6;
    const int l15 = lane & 15;
    const int kg = lane >> 4;

    // Q fragments (pre-scaled by log2(e)/32): lane holds Q[q=l15][d=kg*8+j]
    short8 qf[2];
    {
        const unsigned short* qp =
            qws + ((size_t)(b * NT + qt * 64 + wave * 16 + l15)) * NH + kg * 8;
        qf[0] = *(const short8*)(qp);
        qf[1] = *(const short8*)(qp + 32);
    }

    f32x4 o[4];        // O^T: o[dt][r] = O[q=l15][d = dt*16 + kg*4 + r]
#pragma unroll
    for (int dt = 0; dt < 4; ++dt) o[dt] = f32x4{0.f, 0.f, 0.f, 0.f};
    float m_r = -INFINITY;   // row max (uniform across the row's 4 kg-lanes)
    float l_r = 0.f;         // per-lane PARTIAL sum (own 16 keys)

    // staging assignment: thread -> (row 0..63, seg 0..3 of 32B)
    const int stg_row = threadIdx.x >> 2;
    const int stg_seg = threadIdx.x & 3;
    const unsigned short* kbase =
        kws + ((size_t)(b * NT) + stg_row) * NH + stg_seg * 16;
    const unsigned short* vbase =
        vtws + ((size_t)(b * NH + stg_row)) * NT + stg_seg * 16;
    const int sc0 = (stg_seg * 32) ^ ((stg_row & 7) << 4);
    const int sc1 = (stg_seg * 32 + 16) ^ ((stg_row & 7) << 4);
    char* pw = (char*)Plds + wave * 2048;
    const int pswz = (l15 & 7) << 4;

    // prologue: stage tile k0 into buf 0
    {
        const uint4* kp = (const uint4*)(kbase + (size_t)k0 * 64 * NH);
        uint4 kt0 = kp[0], kt1 = kp[1];
        const uint4* vp = (const uint4*)(vbase + (size_t)k0 * 64);
        uint4 vt0 = vp[0], vt1 = vp[1];
        char* kd = (char*)Kbuf[0] + stg_row * 128;
        char* vd = (char*)Vbuf[0] + stg_row * 128;
        *(uint4*)(kd + sc0) = kt0; *(uint4*)(kd + sc1) = kt1;
        *(uint4*)(vd + sc0) = vt0; *(uint4*)(vd + sc1) = vt1;
    }
    __syncthreads();

    int cur = 0;
    for (int kv = k0; kv < k1; ++kv) {
        // issue next tile's global loads early (hidden under compute)
        uint4 kn0, kn1, vn0, vn1;
        const bool pre = (kv + 1 < k1);
        if (pre) {
            const uint4* kp = (const uint4*)(kbase + (size_t)(kv + 1) * 64 * NH);
            kn0 = kp[0]; kn1 = kp[1];
            const uint4* vp = (const uint4*)(vbase + (size_t)(kv + 1) * 64);
            vn0 = vp[0]; vn1 = vp[1];
        }

        const char* Kb = (const char*)Kbuf[cur];
        const char* Vb = (const char*)Vbuf[cur];

        // S^T = mfma(K, Q): st[jt][r] = S[q=l15][key = jt*16 + kg*4 + r]
        f32x4 st[4];
#pragma unroll
        for (int jt = 0; jt < 4; ++jt) st[jt] = f32x4{0.f, 0.f, 0.f, 0.f};
#pragma unroll
        for (int ks = 0; ks < 2; ++ks) {
            const int cbb = ks * 64 + kg * 16;
#pragma unroll
            for (int jt = 0; jt < 4; ++jt) {
                int krow = jt * 16 + l15;
                short8 kf = *(const short8*)(Kb + krow * 128 +
                                             (cbb ^ ((krow & 7) << 4)));
                st[jt] = __builtin_amdgcn_mfma_f32_16x16x32_bf16(kf, qf[ks], st[jt], 0, 0, 0);
            }
        }

        // causal mask: only the diagonal tile (uniform branch)
        if (kv == qt) {
#pragma unroll
            for (int jt = 0; jt < 4; ++jt)
#pragma unroll
                for (int r = 0; r < 4; ++r)
                    if (jt * 16 + (kg << 2) + r > wave * 16 + l15)
                        st[jt][r] = -1e30f;
        }

        // lane-local max over own 16 keys (no cross-lane)
        float lmax;
        {
            float t0 = fmaxf(fmaxf(st[0][0], st[0][1]), fmaxf(st[0][2], st[0][3]));
            float t1 = fmaxf(fmaxf(st[1][0], st[1][1]), fmaxf(st[1][2], st[1][3]));
            float t2 = fmaxf(fmaxf(st[2][0], st[2][1]), fmaxf(st[2][2], st[2][3]));
            float t3 = fmaxf(fmaxf(st[3][0], st[3][1]), fmaxf(st[3][2], st[3][3]));
            lmax = fmaxf(fmaxf(t0, t1), fmaxf(t2, t3));
        }

        // defer-max: rescale only when some row grew past m+8 (rare)
        if (!__all(lmax <= m_r + 8.0f)) {
            float pmax = lmax;
            pmax = fmaxf(pmax, __shfl_xor(pmax, 16));
            pmax = fmaxf(pmax, __shfl_xor(pmax, 32));
            float mn = fmaxf(m_r, pmax);
            float alpha = __builtin_amdgcn_exp2f(m_r - mn);
            m_r = mn;
            l_r *= alpha;
#pragma unroll
            for (int dt = 0; dt < 4; ++dt)
#pragma unroll
                for (int r = 0; r < 4; ++r)
                    o[dt][r] *= alpha;
        }

        // P = exp2(S - m), bounded by 2^8; accumulate per-lane partial l
#pragma unroll
        for (int jt = 0; jt < 4; ++jt)
#pragma unroll
            for (int r = 0; r < 4; ++r)
                st[jt][r] = __builtin_amdgcn_exp2f(st[jt][r] - m_r);
        {
            float t0 = (st[0][0] + st[0][1]) + (st[0][2] + st[0][3]);
            float t1 = (st[1][0] + st[1][1]) + (st[1][2] + st[1][3]);
            float t2 = (st[2][0] + st[2][1]) + (st[2][2] + st[2][3]);
            float t3 = (st[3][0] + st[3][1]) + (st[3][2] + st[3][3]);
            l_r += (t0 + t1) + (t2 + t3);
        }

        // pack P to bf16, per-wave LDS strip round-trip -> B-frag layout
#pragma unroll
        for (int jt = 0; jt < 4; ++jt) {
            unsigned w0 = cvt_pk_bf16(st[jt][0], st[jt][1]);
            unsigned w1 = cvt_pk_bf16(st[jt][2], st[jt][3]);
            uint2 t; t.x = w0; t.y = w1;
            *(uint2*)(pw + l15 * 128 + ((jt * 32 + kg * 8) ^ pswz)) = t;
        }
        short8 pf[2];
#pragma unroll
        for (int ks = 0; ks < 2; ++ks)
            pf[ks] = *(const short8*)(pw + l15 * 128 + ((ks * 64 + kg * 16) ^ pswz));

        // O^T += mfma(V^T, P^T)
#pragma unroll
        for (int ks = 0; ks < 2; ++ks) {
            const int cbb = ks * 64 + kg * 16;
#pragma unroll
            for (int dt = 0; dt < 4; ++dt) {
                int vrow = dt * 16 + l15;
                short8 vf = *(const short8*)(Vb + vrow * 128 +
                                             (cbb ^ ((vrow & 7) << 4)));
                o[dt] = __builtin_amdgcn_mfma_f32_16x16x32_bf16(vf, pf[ks], o[dt], 0, 0, 0);
            }
        }

        if (pre) {
            __syncthreads();   // all waves done reading buf[cur^1]
            char* kd = (char*)Kbuf[cur ^ 1] + stg_row * 128;
            char* vd = (char*)Vbuf[cur ^ 1] + stg_row * 128;
            *(uint4*)(kd + sc0) = kn0; *(uint4*)(kd + sc1) = kn1;
            *(uint4*)(vd + sc0) = vn0; *(uint4*)(vd + sc1) = vn1;
            __syncthreads();   // writes visible
            cur ^= 1;
        }
    }

    // epilogue: reduce partial l across the row's 4 kg-lanes; store raw O^T + (m,l)
    float lsum = l_r;
    lsum += __shfl_xor(lsum, 16);
    lsum += __shfl_xor(lsum, 32);
    float* orow = op + (wave * 16 + l15) * 64 + (kg << 2);
#pragma unroll
    for (int dt = 0; dt < 4; ++dt)
        *(f32x4*)(orow + dt * 16) = o[dt];
    if (kg == 0) {               // one lane per q-row
        int q = wave * 16 + l15;
        mlp[q] = m_r;
        mlp[64 + q] = lsum;
    }
}

// ---------------- Combine: merge the two KV halves, normalize -----------------
// 512 blocks = (b, qt). O = (eA*OA + eB*OB) / (eA*lA + eB*lB), e = exp2(m - m*).
__global__ __launch_bounds__(256) void combine_kernel(
    const float* __restrict__ opart, const float* __restrict__ mlpart,
    float* __restrict__ out)
{
    const int cid = blockIdx.x;          // = (b<<6)|qt
    const int b = cid >> 6, qt = cid & 63;
    const float* mlA = mlpart + (size_t)cid * 128;
    const float* mlB = mlpart + (size_t)(512 + cid) * 128;
    const f32x4* oA = (const f32x4*)(opart + (size_t)cid * 4096);
    const f32x4* oB = (const f32x4*)(opart + (size_t)(512 + cid) * 4096);
    f32x4* og = (f32x4*)out;

#pragma unroll
    for (int i = 0; i < 4; ++i) {
        int g = threadIdx.x + i * 256;   // 0..1023 f32x4 groups
        int row = g >> 4;
        float mA = mlA[row], lA = mlA[64 + row];
        float mB = mlB[row], lB = mlB[64 + row];
        float ms = fmaxf(mA, mB);
        float eA = __builtin_amdgcn_exp2f(mA - ms);
        float eB = __builtin_amdgcn_exp2f(mB - ms);
        float dinv = __builtin_amdgcn_rcpf(eA * lA + eB * lB);
        f32x4 a = oA[g], c = oB[g];
        f32x4 r;
        r[0] = (eA * a[0] + eB * c[0]) * dinv;
        r[1] = (eA * a[1] + eB * c[1]) * dinv;
        r[2] = (eA * a[2] + eB * c[2]) * dinv;
        r[3] = (eA * a[3] + eB * c[3]) * dinv;
        og[((size_t)(b * NT) + qt * 64 + row) * 16 + (g & 15)] = r;
    }
}

extern "C" void kernel_launch(void* const* d_in, const int* in_sizes, int n_in,
                              void* d_out, int out_size, void* d_ws, size_t ws_size,
                              hipStream_t stream) {
    const float* x  = (const float*)d_in[0];
    const float* Wk = (const float*)d_in[1];
    const float* Wq = (const float*)d_in[2];
    const float* Wv = (const float*)d_in[3];
    float* out = (float*)d_out;

    unsigned short* ws   = (unsigned short*)d_ws;
    const size_t qkv_elems = (size_t)NB * NT * NH;   // 2M elements each
    unsigned short* qws  = ws;
    unsigned short* kws  = qws + qkv_elems;
    unsigned short* vtws = kws + qkv_elems;
    unsigned short* Wt   = vtws + qkv_elems;          // 192*1024 bf16
    float* opart  = (float*)(Wt + (size_t)192 * NC);  // 1024 tiles x 4096 f32
    float* mlpart = opart + (size_t)1024 * 4096;      // 1024 x 128 f32

    wprep_kernel<<<dim3(192), dim3(256), 0, stream>>>(Wk, Wq, Wv, Wt);
    proj_kernel<<<dim3(512), dim3(256), 0, stream>>>(x, Wt, qws, kws, vtws);
    flash_kernel<<<dim3(1024), dim3(256), 0, stream>>>(qws, kws, vtws, opart, mlpart);
    combine_kernel<<<dim3(512), dim3(256), 0, stream>>>(opart, mlpart, out);
}

// Round 7
// 96.564 us; speedup vs baseline: 2.5758x; 1.0158x over previous
//
#include <hip/hip_runtime.h>
#include <hip/hip_bf16.h>

// B=8, T=4096, C=1024, HS=64. Single attention head, causal, scale = C^-0.5.
// Pipeline: wprep (W -> Wt bf16 [192][1024]) ; proj (q,k bf16 [b][t][64], vT bf16 [b][64][t]) ;
//           flash (split-KV causal online-softmax, swapped-operand MFMA, gload_lds staging) ;
//           combine (merge the two KV halves, normalize, fp32 out).
// Q is pre-scaled by log2(e)/32 in proj, so QK^T is directly log2-domain.

typedef __attribute__((ext_vector_type(8))) short short8;
typedef __attribute__((ext_vector_type(4))) float f32x4;

#define NB 8
#define NT 4096
#define NC 1024
#define NH 64

__device__ __forceinline__ unsigned short f2bf(float f) {
    unsigned int u = __builtin_bit_cast(unsigned int, f);
    u += 0x7fffu + ((u >> 16) & 1u);   // RNE
    return (unsigned short)(u >> 16);
}

__device__ __forceinline__ unsigned cvt_pk_bf16(float lo, float hi) {
    unsigned r;
    asm("v_cvt_pk_bf16_f32 %0, %1, %2" : "=v"(r) : "v"(lo), "v"(hi));
    return r;
}

// async global->LDS, 16B per lane; LDS dest = wave-uniform base + lane*16
#define GLOAD16(gp, lp)                                                        \
    __builtin_amdgcn_global_load_lds(                                          \
        (const __attribute__((address_space(1))) void*)(gp),                   \
        (__attribute__((address_space(3))) void*)(lp), 16, 0, 0)

// ---------------- W prep: Wt[n][c] = W_{n/64}[c][n%64] as bf16 -----------------
__global__ __launch_bounds__(256) void wprep_kernel(
    const float* __restrict__ Wk, const float* __restrict__ Wq,
    const float* __restrict__ Wv, unsigned short* __restrict__ Wt)
{
    int n = blockIdx.x;            // 0..191
    int which = n >> 6, h = n & 63;
    const float* W = (which == 0) ? Wk : (which == 1) ? Wq : Wv;
    for (int c = threadIdx.x; c < NC; c += 256)
        Wt[(size_t)n * NC + c] = f2bf(W[(size_t)c * NH + h]);
}

// ---------------- Projection GEMM: [32768 x 1024] @ [1024 x 192] ---------------
// m97-style 2-phase: double-buffered LDS, global_load_lds staging (width 16),
// BK=64. A tile [64 rows][64 k] fp32 (16 KB), B tile [192 n][64 k] bf16 (24 KB).
__global__ __launch_bounds__(256, 2) void proj_kernel(
    const float* __restrict__ x, const unsigned short* __restrict__ Wt,
    unsigned short* __restrict__ qws, unsigned short* __restrict__ kws,
    unsigned short* __restrict__ vtws)
{
    __shared__ float          Albuf[2][64 * 64];           // 2 x 16 KB
    __shared__ unsigned short Blbuf[2][192 * 64];          // 2 x 24 KB

    const int lane = threadIdx.x & 63;
    const int wave = threadIdx.x >> 6;
    const int l15 = lane & 15;
    const int kg = lane >> 4;                  // 0..3
    const int m0 = blockIdx.x * 64;

    const float* aSrc[4];
#pragma unroll
    for (int i = 0; i < 4; ++i) {
        int rlo = lane >> 4;
        int r = 4 * (wave * 4 + i) + rlo;
        int g = (lane & 15) ^ (4 * i + rlo);
        aSrc[i] = x + (size_t)(m0 + r) * NC + g * 4;
    }
    const unsigned short* bSrc[6];
#pragma unroll
    for (int i = 0; i < 6; ++i) {
        int r = 8 * (wave * 6 + i) + (lane >> 3);
        int g = (lane & 7) ^ (lane >> 3);
        bSrc[i] = Wt + (size_t)r * NC + g * 8;
    }

    f32x4 acc[12];
#pragma unroll
    for (int i = 0; i < 12; ++i) acc[i] = f32x4{0.f, 0.f, 0.f, 0.f};

#pragma unroll
    for (int i = 0; i < 4; ++i)
        GLOAD16(aSrc[i], (char*)&Albuf[0][0] + (wave * 4 + i) * 1024);
#pragma unroll
    for (int i = 0; i < 6; ++i)
        GLOAD16(bSrc[i], (char*)&Blbuf[0][0] + (wave * 6 + i) * 1024);
    __syncthreads();

    int buf = 0;
    for (int kc = 0; kc < 16; ++kc) {
        if (kc < 15) {
#pragma unroll
            for (int i = 0; i < 4; ++i)
                GLOAD16(aSrc[i] + (kc + 1) * 64,
                        (char*)&Albuf[buf ^ 1][0] + (wave * 4 + i) * 1024);
#pragma unroll
            for (int i = 0; i < 6; ++i)
                GLOAD16(bSrc[i] + (kc + 1) * 64,
                        (char*)&Blbuf[buf ^ 1][0] + (wave * 6 + i) * 1024);
        }

        const char* Ab = (const char*)&Albuf[buf][0];
        const char* Bb = (const char*)&Blbuf[buf][0];
#pragma unroll
        for (int sub = 0; sub < 2; ++sub) {
            const int r = wave * 16 + l15;
            const int g0 = sub * 8 + kg * 2;
            f32x4 a0 = *(const f32x4*)(Ab + r * 256 + ((g0 ^ l15) * 16));
            f32x4 a1 = *(const f32x4*)(Ab + r * 256 + (((g0 + 1) ^ l15) * 16));
            short8 a;
            a[0] = (short)f2bf(a0[0]); a[1] = (short)f2bf(a0[1]);
            a[2] = (short)f2bf(a0[2]); a[3] = (short)f2bf(a0[3]);
            a[4] = (short)f2bf(a1[0]); a[5] = (short)f2bf(a1[1]);
            a[6] = (short)f2bf(a1[2]); a[7] = (short)f2bf(a1[3]);
#pragma unroll
            for (int nt = 0; nt < 12; ++nt) {
                int rb = nt * 16 + l15;
                short8 bfrag = *(const short8*)(
                    Bb + rb * 128 + ((((sub << 2) + kg) ^ (l15 & 7)) * 16));
                acc[nt] = __builtin_amdgcn_mfma_f32_16x16x32_bf16(a, bfrag, acc[nt], 0, 0, 0);
            }
        }
        __syncthreads();
        buf ^= 1;
    }

    const float cs = 0.04508422f;   // log2(e) / 32  (folded into q)
    const int crow0 = m0 + wave * 16 + (kg << 2);
#pragma unroll
    for (int nt = 0; nt < 12; ++nt) {
        int n = nt * 16 + l15;
        int which = n >> 6;
        int h = n & 63;
#pragma unroll
        for (int r = 0; r < 4; ++r) {
            int gm = crow0 + r;
            float av = acc[nt][r];
            if (which == 1) av *= cs;
            unsigned short v = f2bf(av);
            if (which == 0) {
                kws[(size_t)gm * NH + h] = v;
            } else if (which == 1) {
                qws[(size_t)gm * NH + h] = v;
            } else {
                int bb = gm >> 12, tt = gm & 4095;
                vtws[((size_t)(bb * NH + h)) * NT + tt] = v;
            }
        }
    }
}

// ---------------- Flash attention (causal, swapped operands, split-KV) ---------
// 1024 blocks = 2 KV-halves x (8 batches x 64 q-tiles). 4 waves x 16 q-rows.
// K/V staged via global_load_lds into a double buffer (fire-and-forget: cannot
// be compiler-sunk). Swizzle moved to the global source (rule #21): linear LDS
// dest; lds[r][g] holds K[r][g^(r&7)], so reads XOR the granule with (r&7).
// ONE barrier per iteration: stage(next->buf^1) || compute(buf) -> barrier.
__global__ __launch_bounds__(256) void flash_kernel(
    const unsigned short* __restrict__ qws, const unsigned short* __restrict__ kws,
    const unsigned short* __restrict__ vtws,
    float* __restrict__ opart, float* __restrict__ mlpart)
{
    __shared__ unsigned short Kbuf[2][64 * 64];
    __shared__ unsigned short Vbuf[2][64 * 64];
    __shared__ unsigned short Plds[4 * 16 * 64];   // per-wave 16x64 P strips

    const int id = blockIdx.x;
    const int kvh = id >> 9;           // KV half: 0 = [0,h), 1 = [h,nkv)
    const int rem9 = id & 511;
    const int lighthalf = rem9 >> 8;   // 0: heavy q-tiles, 1: light
    const int rem = rem9 & 255;
    const int b = rem & 7;
    const int i32 = rem >> 3;          // 0..31
    const int qt = lighthalf ? i32 : (63 - i32);
    const int nkv = qt + 1;
    const int hsp = nkv - (nkv >> 1);  // ceil(nkv/2)
    const int k0 = kvh ? hsp : 0;
    const int k1 = kvh ? nkv : hsp;
    const int pid_ = (kvh << 9) | ((b << 6) | qt);

    float* mlp = mlpart + (size_t)pid_ * 128;
    float* op  = opart + (size_t)pid_ * 4096;

    if (k0 >= k1) {                    // empty partition (qt=0, half B)
        f32x4 z = f32x4{0.f, 0.f, 0.f, 0.f};
        f32x4* op4 = (f32x4*)op;
        for (int i = threadIdx.x; i < 1024; i += 256) op4[i] = z;
        if (threadIdx.x < 64) {
            mlp[threadIdx.x] = -INFINITY;
            mlp[64 + threadIdx.x] = 0.f;
        }
        return;
    }

    const int lane = threadIdx.x & 63;
    const int wave = threadIdx.x >> 6;
    const int l15 = lane & 15;
    const int kg = lane >> 4;

    // ---- staging sources (pre-inverse-swizzled, loop-invariant per lane) ----
    // Instr i (0..7) covers tile rows 8i..8i+7; wave handles i = 2*wave + j.
    // lane l -> row 8i + (l>>3), granule (l&7); source granule (l&7)^(l>>3).
    const int sg = (lane & 7) ^ (lane >> 3);   // swizzled source granule
    const unsigned short* kSrc[2];
    const unsigned short* vSrc[2];
#pragma unroll
    for (int j = 0; j < 2; ++j) {
        int r = 16 * wave + 8 * j + (lane >> 3);   // tile-local row 0..63
        kSrc[j] = kws + ((size_t)(b * NT) + r) * NH + sg * 8;
        vSrc[j] = vtws + ((size_t)(b * NH + r)) * NT + sg * 8;
    }

    // Q fragments (pre-scaled by log2(e)/32): lane holds Q[q=l15][d=kg*8+j]
    short8 qf[2];
    {
        const unsigned short* qp =
            qws + ((size_t)(b * NT + qt * 64 + wave * 16 + l15)) * NH + kg * 8;
        qf[0] = *(const short8*)(qp);
        qf[1] = *(const short8*)(qp + 32);
    }

    f32x4 o[4];        // O^T: o[dt][r] = O[q=l15][d = dt*16 + kg*4 + r]
#pragma unroll
    for (int dt = 0; dt < 4; ++dt) o[dt] = f32x4{0.f, 0.f, 0.f, 0.f};
    float m_r = -INFINITY;   // row max (uniform across the row's 4 kg-lanes)
    float l_r = 0.f;         // per-lane PARTIAL sum (own 16 keys)

    char* pw = (char*)Plds + wave * 2048;
    const int pswz = (l15 & 7) << 4;

    // prologue: stage tile k0 into buf 0
#pragma unroll
    for (int j = 0; j < 2; ++j) {
        int i = 2 * wave + j;
        GLOAD16(kSrc[j] + (size_t)k0 * 64 * NH, (char*)Kbuf[0] + i * 1024);
        GLOAD16(vSrc[j] + (size_t)k0 * 64,      (char*)Vbuf[0] + i * 1024);
    }
    __syncthreads();

    int cur = 0;
    for (int kv = k0; kv < k1; ++kv) {
        // stage next tile into the other buffer (async, fire-and-forget)
        if (kv + 1 < k1) {
#pragma unroll
            for (int j = 0; j < 2; ++j) {
                int i = 2 * wave + j;
                GLOAD16(kSrc[j] + (size_t)(kv + 1) * 64 * NH,
                        (char*)Kbuf[cur ^ 1] + i * 1024);
                GLOAD16(vSrc[j] + (size_t)(kv + 1) * 64,
                        (char*)Vbuf[cur ^ 1] + i * 1024);
            }
        }

        const char* Kb = (const char*)Kbuf[cur];
        const char* Vb = (const char*)Vbuf[cur];

        // S^T = mfma(K, Q): st[jt][r] = S[q=l15][key = jt*16 + kg*4 + r]
        f32x4 st[4];
#pragma unroll
        for (int jt = 0; jt < 4; ++jt) st[jt] = f32x4{0.f, 0.f, 0.f, 0.f};
#pragma unroll
        for (int ks = 0; ks < 2; ++ks) {
            const int cbb = ks * 64 + kg * 16;
#pragma unroll
            for (int jt = 0; jt < 4; ++jt) {
                int krow = jt * 16 + l15;
                short8 kf = *(const short8*)(Kb + krow * 128 +
                                             (cbb ^ ((krow & 7) << 4)));
                st[jt] = __builtin_amdgcn_mfma_f32_16x16x32_bf16(kf, qf[ks], st[jt], 0, 0, 0);
            }
        }

        // causal mask: only the diagonal tile (uniform branch)
        if (kv == qt) {
#pragma unroll
            for (int jt = 0; jt < 4; ++jt)
#pragma unroll
                for (int r = 0; r < 4; ++r)
                    if (jt * 16 + (kg << 2) + r > wave * 16 + l15)
                        st[jt][r] = -1e30f;
        }

        // lane-local max over own 16 keys (no cross-lane)
        float lmax;
        {
            float t0 = fmaxf(fmaxf(st[0][0], st[0][1]), fmaxf(st[0][2], st[0][3]));
            float t1 = fmaxf(fmaxf(st[1][0], st[1][1]), fmaxf(st[1][2], st[1][3]));
            float t2 = fmaxf(fmaxf(st[2][0], st[2][1]), fmaxf(st[2][2], st[2][3]));
            float t3 = fmaxf(fmaxf(st[3][0], st[3][1]), fmaxf(st[3][2], st[3][3]));
            lmax = fmaxf(fmaxf(t0, t1), fmaxf(t2, t3));
        }

        // defer-max: rescale only when some row grew past m+8 (rare)
        if (!__all(lmax <= m_r + 8.0f)) {
            float pmax = lmax;
            pmax = fmaxf(pmax, __shfl_xor(pmax, 16));
            pmax = fmaxf(pmax, __shfl_xor(pmax, 32));
            float mn = fmaxf(m_r, pmax);
            float alpha = __builtin_amdgcn_exp2f(m_r - mn);
            m_r = mn;
            l_r *= alpha;
#pragma unroll
            for (int dt = 0; dt < 4; ++dt)
#pragma unroll
                for (int r = 0; r < 4; ++r)
                    o[dt][r] *= alpha;
        }

        // P = exp2(S - m), bounded by 2^8; accumulate per-lane partial l
#pragma unroll
        for (int jt = 0; jt < 4; ++jt)
#pragma unroll
            for (int r = 0; r < 4; ++r)
                st[jt][r] = __builtin_amdgcn_exp2f(st[jt][r] - m_r);
        {
            float t0 = (st[0][0] + st[0][1]) + (st[0][2] + st[0][3]);
            float t1 = (st[1][0] + st[1][1]) + (st[1][2] + st[1][3]);
            float t2 = (st[2][0] + st[2][1]) + (st[2][2] + st[2][3]);
            float t3 = (st[3][0] + st[3][1]) + (st[3][2] + st[3][3]);
            l_r += (t0 + t1) + (t2 + t3);
        }

        // pack P to bf16, per-wave LDS strip round-trip -> B-frag layout
#pragma unroll
        for (int jt = 0; jt < 4; ++jt) {
            unsigned w0 = cvt_pk_bf16(st[jt][0], st[jt][1]);
            unsigned w1 = cvt_pk_bf16(st[jt][2], st[jt][3]);
            uint2 t; t.x = w0; t.y = w1;
            *(uint2*)(pw + l15 * 128 + ((jt * 32 + kg * 8) ^ pswz)) = t;
        }
        short8 pf[2];
#pragma unroll
        for (int ks = 0; ks < 2; ++ks)
            pf[ks] = *(const short8*)(pw + l15 * 128 + ((ks * 64 + kg * 16) ^ pswz));

        // O^T += mfma(V^T, P^T)
#pragma unroll
        for (int ks = 0; ks < 2; ++ks) {
            const int cbb = ks * 64 + kg * 16;
#pragma unroll
            for (int dt = 0; dt < 4; ++dt) {
                int vrow = dt * 16 + l15;
                short8 vf = *(const short8*)(Vb + vrow * 128 +
                                             (cbb ^ ((vrow & 7) << 4)));
                o[dt] = __builtin_amdgcn_mfma_f32_16x16x32_bf16(vf, pf[ks], o[dt], 0, 0, 0);
            }
        }

        // single barrier: drains staging vmcnt + this iter's LDS reads,
        // making buf[cur] safe to overwrite and buf[cur^1] ready to read.
        __syncthreads();
        cur ^= 1;
    }

    // epilogue: reduce partial l across the row's 4 kg-lanes; store raw O^T + (m,l)
    float lsum = l_r;
    lsum += __shfl_xor(lsum, 16);
    lsum += __shfl_xor(lsum, 32);
    float* orow = op + (wave * 16 + l15) * 64 + (kg << 2);
#pragma unroll
    for (int dt = 0; dt < 4; ++dt)
        *(f32x4*)(orow + dt * 16) = o[dt];
    if (kg == 0) {               // one lane per q-row
        int q = wave * 16 + l15;
        mlp[q] = m_r;
        mlp[64 + q] = lsum;
    }
}

// ---------------- Combine: merge the two KV halves, normalize -----------------
// 512 blocks = (b, qt). O = (eA*OA + eB*OB) / (eA*lA + eB*lB), e = exp2(m - m*).
__global__ __launch_bounds__(256) void combine_kernel(
    const float* __restrict__ opart, const float* __restrict__ mlpart,
    float* __restrict__ out)
{
    const int cid = blockIdx.x;          // = (b<<6)|qt
    const int b = cid >> 6, qt = cid & 63;
    const float* mlA = mlpart + (size_t)cid * 128;
    const float* mlB = mlpart + (size_t)(512 + cid) * 128;
    const f32x4* oA = (const f32x4*)(opart + (size_t)cid * 4096);
    const f32x4* oB = (const f32x4*)(opart + (size_t)(512 + cid) * 4096);
    f32x4* og = (f32x4*)out;

#pragma unroll
    for (int i = 0; i < 4; ++i) {
        int g = threadIdx.x + i * 256;   // 0..1023 f32x4 groups
        int row = g >> 4;
        float mA = mlA[row], lA = mlA[64 + row];
        float mB = mlB[row], lB = mlB[64 + row];
        float ms = fmaxf(mA, mB);
        float eA = __builtin_amdgcn_exp2f(mA - ms);
        float eB = __builtin_amdgcn_exp2f(mB - ms);
        float dinv = __builtin_amdgcn_rcpf(eA * lA + eB * lB);
        f32x4 a = oA[g], c = oB[g];
        f32x4 r;
        r[0] = (eA * a[0] + eB * c[0]) * dinv;
        r[1] = (eA * a[1] + eB * c[1]) * dinv;
        r[2] = (eA * a[2] + eB * c[2]) * dinv;
        r[3] = (eA * a[3] + eB * c[3]) * dinv;
        og[((size_t)(b * NT) + qt * 64 + row) * 16 + (g & 15)] = r;
    }
}

extern "C" void kernel_launch(void* const* d_in, const int* in_sizes, int n_in,
                              void* d_out, int out_size, void* d_ws, size_t ws_size,
                              hipStream_t stream) {
    const float* x  = (const float*)d_in[0];
    const float* Wk = (const float*)d_in[1];
    const float* Wq = (const float*)d_in[2];
    const float* Wv = (const float*)d_in[3];
    float* out = (float*)d_out;

    unsigned short* ws   = (unsigned short*)d_ws;
    const size_t qkv_elems = (size_t)NB * NT * NH;   // 2M elements each
    unsigned short* qws  = ws;
    unsigned short* kws  = qws + qkv_elems;
    unsigned short* vtws = kws + qkv_elems;
    unsigned short* Wt   = vtws + qkv_elems;          // 192*1024 bf16
    float* opart  = (float*)(Wt + (size_t)192 * NC);  // 1024 tiles x 4096 f32
    float* mlpart = opart + (size_t)1024 * 4096;      // 1024 x 128 f32

    wprep_kernel<<<dim3(192), dim3(256), 0, stream>>>(Wk, Wq, Wv, Wt);
    proj_kernel<<<dim3(512), dim3(256), 0, stream>>>(x, Wt, qws, kws, vtws);
    flash_kernel<<<dim3(1024), dim3(256), 0, stream>>>(qws, kws, vtws, opart, mlpart);
    combine_kernel<<<dim3(512), dim3(256), 0, stream>>>(opart, mlpart, out);
}